// Round 4
// baseline (521.130 us; speedup 1.0000x reference)
//
#include <hip/hip_runtime.h>
#include <stdint.h>

#define B_ 16
#define H_ 64
#define W_ 64
#define D_ 64
#define C_ 16
#define K_ 5
#define N_ 4096
#define NC_ 8          // attention n-chunks
#define CS_ 512        // chunk size = N_/NC_
#define EPS 1e-5f

typedef __attribute__((ext_vector_type(8))) short bf16x8;
typedef __attribute__((ext_vector_type(4))) float f32x4;

__device__ __forceinline__ float wsum64(float v){
  #pragma unroll
  for(int o=1;o<64;o<<=1) v += __shfl_xor(v,o,64);
  return v;
}
__device__ __forceinline__ float wmax64(float v){
  #pragma unroll
  for(int o=1;o<64;o<<=1) v = fmaxf(v, __shfl_xor(v,o,64));
  return v;
}
__device__ __forceinline__ float wmin64(float v){
  #pragma unroll
  for(int o=1;o<64;o<<=1) v = fminf(v, __shfl_xor(v,o,64));
  return v;
}
__device__ __forceinline__ uint16_t f2bf(float f){
  uint32_t u = __float_as_uint(f);
  u += 0x7fffu + ((u>>16)&1u);
  return (uint16_t)(u>>16);
}
__device__ __forceinline__ void bf8_to_f(uint4 u, float* x){
  x[0]=__uint_as_float(u.x<<16); x[1]=__uint_as_float(u.x&0xffff0000u);
  x[2]=__uint_as_float(u.y<<16); x[3]=__uint_as_float(u.y&0xffff0000u);
  x[4]=__uint_as_float(u.z<<16); x[5]=__uint_as_float(u.z&0xffff0000u);
  x[6]=__uint_as_float(u.w<<16); x[7]=__uint_as_float(u.w&0xffff0000u);
}

// k_pre: fgpos (bid 0-4) + counter zero + folded-bias precompute (bid 5-6)
// + scaled-weight copies wqp/wrp (bid 7-38) + slot init (bid 39-58)
__global__ __launch_bounds__(256) void k_pre(
    const float* __restrict__ mask, const float* __restrict__ noise,
    const float* __restrict__ mu, const float* __restrict__ lsg,
    const float* __restrict__ wm, const float* __restrict__ bm, const float* __restrict__ lnkb,
    const float* __restrict__ wk, const float* __restrict__ wv, const float* __restrict__ lnfb,
    const float* __restrict__ wq, const float* __restrict__ lnqg, const float* __restrict__ lnqb,
    const float* __restrict__ wres, const float* __restrict__ bres,
    const float* __restrict__ lnrg, const float* __restrict__ lnrb,
    float* __restrict__ ws_fg, float* __restrict__ out_fg,
    float* __restrict__ bm2, float* __restrict__ fkb, float* __restrict__ fvb,
    float* __restrict__ qb, float* __restrict__ br2,
    float* __restrict__ wqp, float* __restrict__ wrp,
    float* __restrict__ slot, int* __restrict__ cnt){
  int bid=blockIdx.x, tid=threadIdx.x;
  if(bid<5){
    int k=bid;
    if(bid==0 && tid<80) cnt[tid]=0;
    float sm=0.f, sx=0.f, sy=0.f;
    for(int p=tid; p<H_*W_; p+=256){
      int i=p>>6, j=p&63;
      float m = mask[k*H_*W_ + p];
      float x = -1.f + (2.f/63.f)*j;
      float y = -1.f + (2.f/63.f)*i;
      sm+=m; sx+=m*x; sy+=m*y;
    }
    __shared__ float r0[4], r1[4], r2[4];
    int wid=tid>>6, lane=tid&63;
    sm=wsum64(sm); sx=wsum64(sx); sy=wsum64(sy);
    if(lane==0){ r0[wid]=sm; r1[wid]=sx; r2[wid]=sy; }
    __syncthreads();
    if(tid==0){
      float tm=r0[0]+r0[1]+r0[2]+r0[3];
      float tx=r1[0]+r1[1]+r1[2]+r1[3];
      float ty=r2[0]+r2[1]+r2[2]+r2[3];
      float px = tx/(tm+1e-5f), py = ty/(tm+1e-5f);
      ws_fg[k*2+0]=px; ws_fg[k*2+1]=py;
      for(int b=0;b<B_;b++){ out_fg[(b*K_+k)*2+0]=px; out_fg[(b*K_+k)*2+1]=py; }
    }
  } else if(bid==5){
    int sel=tid>>6, o=tid&63; float s=0.f;
    if(sel==0){ s=bm[o]; for(int d=0;d<64;d++) s+=lnkb[d]*wm[o*64+d]; bm2[o]=s; }
    else if(sel==1){ for(int d=0;d<64;d++) s+=lnqb[d]*wq[o*64+d]; qb[o]=0.125f*s; }
    else if(sel==2){ for(int d=0;d<64;d++) s+=lnrb[d]*wres[o*64+d]; br2[o]=s+bres[o]; }
    else { for(int d=0;d<64;d++) s+=lnfb[d]*wk[o*64+d]; fkb[o]=s; }
  } else if(bid==6){
    if(tid<64){ int o=tid; float s=0.f; for(int d=0;d<64;d++) s+=lnfb[d]*wv[o*64+d]; fvb[o]=s; }
  } else if(bid<39){
    int i=(bid-7)*256+tid;
    if(i<4096) wqp[i]=0.125f*lnqg[i&63]*wq[i];
    else { int j=i-4096; wrp[j]=lnrg[j&63]*wres[j]; }
  } else {
    int i=(bid-39)*256+tid;
    if(i<B_*K_*D_){ int d=i&63; slot[i]=mu[d]+expf(lsg[d])*noise[i]; }
  }
}

// grid_embed (K,N,D) -> bf16 packed pairs
__global__ void k_gridemb(const float* __restrict__ wg, const float* __restrict__ bg,
                          const float* __restrict__ ws_fg, uint32_t* __restrict__ ge){
  int idx = blockIdx.x*256 + threadIdx.x;   // < K*N*32
  int dp = idx & 31;
  int n = (idx>>5) & (N_-1);
  int k = idx >> 17;
  int j = n & 63, i = n >> 6;
  float rx = (-1.f + (2.f/63.f)*j) - ws_fg[k*2+0];
  float ry = (-1.f + (2.f/63.f)*i) - ws_fg[k*2+1];
  int d0 = dp*2, d1 = dp*2+1;
  float v0 = rx*(wg[d0*4+0]-wg[d0*4+2]) + ry*(wg[d0*4+1]-wg[d0*4+3]) + bg[d0];
  float v1 = rx*(wg[d1*4+0]-wg[d1*4+2]) + ry*(wg[d1*4+1]-wg[d1*4+3]) + bg[d1];
  ge[idx] = (uint32_t)f2bf(v0) | ((uint32_t)f2bf(v1)<<16);
}

// feat LN-fold + fk/fv = (dfrs)@(g.wk).T + fkb  (MFMA, bf16 out) ; + color LN
__global__ __launch_bounds__(256) void k_featln(const float* __restrict__ feat,
    const float* __restrict__ wk, const float* __restrict__ wv, const float* __restrict__ gf,
    const float* __restrict__ fkb, const float* __restrict__ fvb,
    const float* __restrict__ fc, const float* __restrict__ gc, const float* __restrict__ bc,
    uint16_t* __restrict__ fko, uint16_t* __restrict__ fvo, float* __restrict__ fcn){
  int tid=threadIdx.x, wid=tid>>6, lane=tid&63;
  int q=lane>>4, c=lane&15;
  size_t row = (size_t)blockIdx.x*64 + wid*16 + c;
  const float* xp = feat + row*64;
  float x[16];
  *(float4*)&x[0]  = *(const float4*)(xp + q*8);
  *(float4*)&x[4]  = *(const float4*)(xp + q*8 + 4);
  *(float4*)&x[8]  = *(const float4*)(xp + 32 + q*8);
  *(float4*)&x[12] = *(const float4*)(xp + 36 + q*8);
  float s=0.f;
  #pragma unroll
  for(int i=0;i<16;i++) s+=x[i];
  s += __shfl_xor(s,16,64); s += __shfl_xor(s,32,64);
  float mean = s*(1.f/64.f);
  float v=0.f;
  #pragma unroll
  for(int i=0;i<16;i++){ float d=x[i]-mean; v+=d*d; }
  v += __shfl_xor(v,16,64); v += __shfl_xor(v,32,64);
  float rs = rsqrtf(v*(1.f/64.f)+EPS);
  float gl[16];
  *(float4*)&gl[0]  = *(const float4*)(gf + q*8);
  *(float4*)&gl[4]  = *(const float4*)(gf + q*8 + 4);
  *(float4*)&gl[8]  = *(const float4*)(gf + 32 + q*8);
  *(float4*)&gl[12] = *(const float4*)(gf + 36 + q*8);
  bf16x8 A0, A1;
  #pragma unroll
  for(int j=0;j<8;j++){
    A0[j] = (short)f2bf((x[j]  -mean)*rs);
    A1[j] = (short)f2bf((x[8+j]-mean)*rs);
  }
  #pragma unroll
  for(int mat=0;mat<2;mat++){
    const float* w = mat? wv : wk;
    const float* fb = mat? fvb : fkb;
    uint16_t* o = (mat? fvo : fko) + row*64;
    #pragma unroll
    for(int ot=0; ot<4; ot++){
      const float* wp = w + (size_t)(ot*16+c)*64 + q*8;
      bf16x8 W0, W1;
      #pragma unroll
      for(int j=0;j<8;j++){ W0[j]=(short)f2bf(wp[j]*gl[j]); W1[j]=(short)f2bf(wp[32+j]*gl[8+j]); }
      float4 bq = *(const float4*)(fb + ot*16 + q*4);
      f32x4 acc = {bq.x,bq.y,bq.z,bq.w};
      acc = __builtin_amdgcn_mfma_f32_16x16x32_bf16(W0, A0, acc, 0,0,0);
      acc = __builtin_amdgcn_mfma_f32_16x16x32_bf16(W1, A1, acc, 0,0,0);
      uint2 u;
      u.x = (uint32_t)f2bf(acc[0]) | ((uint32_t)f2bf(acc[1])<<16);
      u.y = (uint32_t)f2bf(acc[2]) | ((uint32_t)f2bf(acc[3])<<16);
      *(uint2*)(o + ot*16 + q*4) = u;
    }
  }
  // color LN (C=16), 64 rows per block
  int r16=tid>>4, cc=tid&15;
  #pragma unroll
  for(int i=0;i<4;i++){
    size_t row2 = (size_t)blockIdx.x*64 + i*16 + r16;
    float xv = fc[row2*16+cc];
    float ss=xv;
    #pragma unroll
    for(int o=1;o<16;o<<=1) ss += __shfl_xor(ss,o,16);
    float m2 = ss*(1.f/16.f);
    float df = xv-m2;
    float v2 = df*df;
    #pragma unroll
    for(int o=1;o<16;o<<=1) v2 += __shfl_xor(v2,o,16);
    fcn[row2*16+cc] = df*rsqrtf(v2*(1.f/16.f)+EPS)*gc[cc] + bc[cc];
  }
}

// K/V = LN-fold(f{k,v}+ge)@(g.wm).T + bm2 -> bf16. MFMA, 4 row-tiles/wave.
__global__ __launch_bounds__(256) void k_buildkv(const uint16_t* __restrict__ fk,
    const uint16_t* __restrict__ fv, const uint16_t* __restrict__ ge,
    const float* __restrict__ gkv, const float* __restrict__ wm, const float* __restrict__ bm2,
    uint16_t* __restrict__ Kw, uint16_t* __restrict__ Vw){
  int tid=threadIdx.x, wid=tid>>6, lane=tid&63;
  int q=lane>>4, c=lane&15;
  int k = blockIdx.y, b = blockIdx.z;
  float gl[16];
  *(float4*)&gl[0]  = *(const float4*)(gkv + q*8);
  *(float4*)&gl[4]  = *(const float4*)(gkv + q*8 + 4);
  *(float4*)&gl[8]  = *(const float4*)(gkv + 32 + q*8);
  *(float4*)&gl[12] = *(const float4*)(gkv + 36 + q*8);
  bf16x8 Wf[4][2];
  #pragma unroll
  for(int ot=0;ot<4;ot++){
    const float* wp = wm + (size_t)(ot*16+c)*64 + q*8;
    #pragma unroll
    for(int j=0;j<8;j++){ Wf[ot][0][j]=(short)f2bf(wp[j]*gl[j]); Wf[ot][1][j]=(short)f2bf(wp[32+j]*gl[8+j]); }
  }
  float bmv[4][4];
  #pragma unroll
  for(int ot=0;ot<4;ot++) *(float4*)&bmv[ot][0] = *(const float4*)(bm2 + ot*16 + q*4);

  for(int t=0;t<4;t++){
    int n = blockIdx.x*256 + t*64 + wid*16 + c;
    const uint16_t* gp = ge + ((size_t)k*N_ + n)*64;
    float ga[16];
    bf8_to_f(*(const uint4*)(gp + q*8), &ga[0]);
    bf8_to_f(*(const uint4*)(gp + 32 + q*8), &ga[8]);
    #pragma unroll
    for(int mat=0;mat<2;mat++){
      const uint16_t* fp = (mat? fv : fk) + ((size_t)b*N_ + n)*64;
      float x[16];
      bf8_to_f(*(const uint4*)(fp + q*8), &x[0]);
      bf8_to_f(*(const uint4*)(fp + 32 + q*8), &x[8]);
      #pragma unroll
      for(int i=0;i<16;i++) x[i]+=ga[i];
      float s=0.f;
      #pragma unroll
      for(int i=0;i<16;i++) s+=x[i];
      s += __shfl_xor(s,16,64); s += __shfl_xor(s,32,64);
      float mean = s*(1.f/64.f);
      float v=0.f;
      #pragma unroll
      for(int i=0;i<16;i++){ float d=x[i]-mean; v+=d*d; }
      v += __shfl_xor(v,16,64); v += __shfl_xor(v,32,64);
      float rs = rsqrtf(v*(1.f/64.f)+EPS);
      bf16x8 A0, A1;
      #pragma unroll
      for(int j=0;j<8;j++){
        A0[j] = (short)f2bf((x[j]  -mean)*rs);
        A1[j] = (short)f2bf((x[8+j]-mean)*rs);
      }
      uint16_t* outb = (mat? Vw : Kw) + (((size_t)(b*K_+k))*N_)*64;
      #pragma unroll
      for(int ot=0; ot<4; ot++){
        f32x4 acc = {bmv[ot][0],bmv[ot][1],bmv[ot][2],bmv[ot][3]};
        acc = __builtin_amdgcn_mfma_f32_16x16x32_bf16(Wf[ot][0], A0, acc, 0,0,0);
        acc = __builtin_amdgcn_mfma_f32_16x16x32_bf16(Wf[ot][1], A1, acc, 0,0,0);
        uint2 u;
        u.x = (uint32_t)f2bf(acc[0]) | ((uint32_t)f2bf(acc[1])<<16);
        u.y = (uint32_t)f2bf(acc[2]) | ((uint32_t)f2bf(acc[3])<<16);
        *(uint2*)(outb + (size_t)n*64 + ot*16 + q*4) = u;
      }
    }
  }
}

// logits chunk (+ fused q on wave 0) + chunk softmax stats
template<bool FINAL>
__global__ __launch_bounds__(256) void k_logits(const uint16_t* __restrict__ Kw,
    const float* __restrict__ slot, const float* __restrict__ wqp, const float* __restrict__ qb,
    float* __restrict__ lgt, float* __restrict__ red){
  __shared__ float qs[64];
  __shared__ float rm[4], rs_[4], rn[4];
  int chunk=blockIdx.x, bk=blockIdx.y;
  int tid=threadIdx.x, wid=tid>>6, lane=tid&63;
  if(wid==0){
    float x = slot[bk*64+lane];
    float m = wsum64(x)*(1.f/64.f);
    float df = x-m;
    float var = wsum64(df*df)*(1.f/64.f);
    float dr = df*rsqrtf(var+EPS);
    float a = qb[lane];
    #pragma unroll
    for(int d=0;d<64;d++) a += __shfl(dr,d,64)*wqp[lane*64+d];
    qs[lane]=a;
  }
  __syncthreads();
  const uint4* Kb = (const uint4*)(Kw + (size_t)bk*N_*64) + (size_t)chunk*CS_*8;
  float l[2];
  #pragma unroll
  for(int i=0;i<2;i++){
    int n = tid + i*256;
    float a=0.f;
    #pragma unroll
    for(int j=0;j<8;j++){
      uint4 u = Kb[(size_t)n*8+j];
      a += __uint_as_float(u.x<<16)          * qs[j*8+0]
         + __uint_as_float(u.x&0xffff0000u)  * qs[j*8+1]
         + __uint_as_float(u.y<<16)          * qs[j*8+2]
         + __uint_as_float(u.y&0xffff0000u)  * qs[j*8+3]
         + __uint_as_float(u.z<<16)          * qs[j*8+4]
         + __uint_as_float(u.z&0xffff0000u)  * qs[j*8+5]
         + __uint_as_float(u.w<<16)          * qs[j*8+6]
         + __uint_as_float(u.w&0xffff0000u)  * qs[j*8+7];
    }
    l[i]=a;
    lgt[(size_t)bk*N_ + chunk*CS_ + n] = a;
  }
  float wm_ = wmax64(fmaxf(l[0],l[1]));
  if(lane==0) rm[wid]=wm_;
  if(FINAL){ float mn=wmin64(fminf(l[0],l[1])); if(lane==0) rn[wid]=mn; }
  __syncthreads();
  float m_c = fmaxf(fmaxf(rm[0],rm[1]),fmaxf(rm[2],rm[3]));
  float s = __expf(l[0]-m_c)+__expf(l[1]-m_c);
  s = wsum64(s);
  if(lane==0) rs_[wid]=s;
  __syncthreads();
  if(tid==0){
    float* rp = red + ((size_t)bk*NC_+chunk)*4;
    rp[0]=m_c;
    rp[1]=rs_[0]+rs_[1]+rs_[2]+rs_[3];
    if(FINAL) rp[2]=fminf(fminf(rn[0],rn[1]),fminf(rn[2],rn[3]));
  }
}

// chunk p + partial upd=p@V (+FINAL: p@featc, out_attn); last block per bk does GRU/final
template<bool FINAL>
__global__ __launch_bounds__(256) void k_updv(const uint16_t* __restrict__ Vw,
    const float* __restrict__ lgt, const float* __restrict__ red,
    const float* __restrict__ featc,
    float* __restrict__ part, float* __restrict__ partc, float* __restrict__ out_attn,
    float* __restrict__ slot,
    const float* __restrict__ wih, const float* __restrict__ whh,
    const float* __restrict__ bih, const float* __restrict__ bhh,
    const float* __restrict__ wrp, const float* __restrict__ br2,
    float* __restrict__ out_slot, int* __restrict__ cnt){
  __shared__ float ps[CS_];
  __shared__ float pw[4][64];
  __shared__ float pcz[4][16];
  __shared__ int lastf;
  int chunk=blockIdx.x, bk=blockIdx.y, b=bk/K_;
  int tid=threadIdx.x, wid=tid>>6, lane=tid&63, sub=lane>>4, c4=lane&15;
  const float* rp = red + (size_t)bk*NC_*4;
  float M=-1e30f;
  #pragma unroll
  for(int i=0;i<NC_;i++) M = fmaxf(M, rp[i*4]);
  float S=0.f;
  #pragma unroll
  for(int i=0;i<NC_;i++) S += rp[i*4+1]*__expf(rp[i*4]-M);
  float invS = 1.f/S;
  float amin=0.f, dinv=0.f;
  if(FINAL){
    float LMIN=1e30f;
    #pragma unroll
    for(int i=0;i<NC_;i++) LMIN=fminf(LMIN, rp[i*4+2]);
    amin = __expf(LMIN-M)*invS;
    dinv = 1.f/(invS - amin + 1e-5f);
  }
  const float* lp = lgt + (size_t)bk*N_ + chunk*CS_;
  #pragma unroll
  for(int i=0;i<2;i++){
    int n = tid + i*256;
    float p = __expf(lp[n]-M)*invS;
    ps[n]=p;
    if(FINAL) out_attn[(size_t)bk*N_ + chunk*CS_ + n] = (p - amin)*dinv;
  }
  __syncthreads();
  const uint2* Vb = (const uint2*)(Vw + (size_t)bk*N_*64) + (size_t)chunk*CS_*16;
  const float* Fb = featc + ((size_t)b*N_ + chunk*CS_)*16;
  float a0=0.f,a1=0.f,a2=0.f,a3=0.f,ac=0.f;
  for(int t=0;t<32;t++){
    int n = wid*128 + t*4 + sub;
    float p = ps[n];
    uint2 u = Vb[(size_t)n*16 + c4];
    a0 += p*__uint_as_float(u.x<<16);
    a1 += p*__uint_as_float(u.x&0xffff0000u);
    a2 += p*__uint_as_float(u.y<<16);
    a3 += p*__uint_as_float(u.y&0xffff0000u);
    if(FINAL) ac += p*Fb[(size_t)n*16 + c4];
  }
  a0+=__shfl_xor(a0,16,64); a0+=__shfl_xor(a0,32,64);
  a1+=__shfl_xor(a1,16,64); a1+=__shfl_xor(a1,32,64);
  a2+=__shfl_xor(a2,16,64); a2+=__shfl_xor(a2,32,64);
  a3+=__shfl_xor(a3,16,64); a3+=__shfl_xor(a3,32,64);
  if(FINAL){ ac+=__shfl_xor(ac,16,64); ac+=__shfl_xor(ac,32,64); }
  if(lane<16){
    pw[wid][lane*4+0]=a0; pw[wid][lane*4+1]=a1;
    pw[wid][lane*4+2]=a2; pw[wid][lane*4+3]=a3;
    if(FINAL) pcz[wid][lane]=ac;
  }
  __syncthreads();
  if(tid<64){
    part[((size_t)bk*NC_+chunk)*64 + tid] = pw[0][tid]+pw[1][tid]+pw[2][tid]+pw[3][tid];
  }
  if(FINAL && tid<16){
    partc[((size_t)bk*NC_+chunk)*16 + tid] = pcz[0][tid]+pcz[1][tid]+pcz[2][tid]+pcz[3][tid];
  }
  // last-block-per-bk tail: GRU (non-final) or output write (final)
  __syncthreads();
  if(tid==0){
    __threadfence();
    int old = atomicAdd(&cnt[bk], 1);
    lastf = (old==NC_-1);
    if(lastf) cnt[bk]=0;
  }
  __syncthreads();
  if(!lastf) return;
  __threadfence();
  if(wid!=0) return;
  if(!FINAL){
    float x=0.f;
    #pragma unroll
    for(int cch=0;cch<NC_;cch++) x += part[((size_t)bk*NC_+cch)*64+lane];
    float hp=slot[bk*64+lane];
    float gir=bih[lane], giz=bih[64+lane], gin=bih[128+lane];
    float ghr=bhh[lane], ghz=bhh[64+lane], ghn=bhh[128+lane];
    #pragma unroll
    for(int d=0;d<64;d++){
      float xd=__shfl(x,d,64), hd=__shfl(hp,d,64);
      gir+=xd*wih[lane*64+d];
      giz+=xd*wih[(64+lane)*64+d];
      gin+=xd*wih[(128+lane)*64+d];
      ghr+=hd*whh[lane*64+d];
      ghz+=hd*whh[(64+lane)*64+d];
      ghn+=hd*whh[(128+lane)*64+d];
    }
    float r=1.f/(1.f+expf(-(gir+ghr)));
    float z=1.f/(1.f+expf(-(giz+ghz)));
    float nn=tanhf(gin+r*ghn);
    float sp=(1.f-z)*nn+z*hp;
    float m=wsum64(sp)*(1.f/64.f); float df=sp-m;
    float var=wsum64(df*df)*(1.f/64.f);
    float dr=df*rsqrtf(var+EPS);
    float a=br2[lane]+hp;
    #pragma unroll
    for(int d=0;d<64;d++) a+=__shfl(dr,d,64)*wrp[lane*64+d];
    slot[bk*64+lane]=a;
  } else {
    out_slot[bk*80+lane]=slot[bk*64+lane];
    if(lane<16){
      float s2=0.f;
      #pragma unroll
      for(int cch=0;cch<NC_;cch++) s2 += partc[((size_t)bk*NC_+cch)*16+lane];
      out_slot[bk*80+64+lane]=s2;
    }
  }
}

extern "C" void kernel_launch(void* const* d_in, const int* in_sizes, int n_in,
                              void* d_out, int out_size, void* d_ws, size_t ws_size,
                              hipStream_t stream){
  (void)in_sizes; (void)n_in; (void)out_size; (void)ws_size;
  const float* feat = (const float*)d_in[0];
  const float* featc= (const float*)d_in[1];
  const float* mask = (const float*)d_in[2];
  const float* noise= (const float*)d_in[3];
  const float* mu   = (const float*)d_in[4];
  const float* lsg  = (const float*)d_in[5];
  const float* wg   = (const float*)d_in[6];
  const float* bg   = (const float*)d_in[7];
  const float* wk   = (const float*)d_in[8];
  const float* wv   = (const float*)d_in[9];
  const float* lnkg = (const float*)d_in[10];
  const float* lnkb = (const float*)d_in[11];
  const float* wm   = (const float*)d_in[12];
  const float* bm   = (const float*)d_in[13];
  const float* lnqg = (const float*)d_in[14];
  const float* lnqb = (const float*)d_in[15];
  const float* wq   = (const float*)d_in[16];
  const float* wih  = (const float*)d_in[17];
  const float* whh  = (const float*)d_in[18];
  const float* bih  = (const float*)d_in[19];
  const float* bhh  = (const float*)d_in[20];
  const float* lnfg = (const float*)d_in[21];
  const float* lnfb = (const float*)d_in[22];
  const float* lncg = (const float*)d_in[23];
  const float* lncb = (const float*)d_in[24];
  const float* lnrg = (const float*)d_in[25];
  const float* lnrb = (const float*)d_in[26];
  const float* wres = (const float*)d_in[27];
  const float* bres = (const float*)d_in[28];

  float* out = (float*)d_out;
  float* out_slot = out;          // (B,K,80)
  float* out_fg   = out + 6400;   // (B,K,2)
  float* out_attn = out + 6560;   // (B,K,N)

  float* wsf     = (float*)d_ws;
  float* ws_fg   = wsf;                                // 16
  float* ws_bm2  = wsf + 16;                           // 64
  float* ws_fkb  = ws_bm2 + 64;                        // 64
  float* ws_fvb  = ws_fkb + 64;                        // 64
  float* ws_qb   = ws_fvb + 64;                        // 64
  float* ws_br2  = ws_qb + 64;                         // 64
  float* ws_wqp  = ws_br2 + 64;                        // 4096
  float* ws_wrp  = ws_wqp + 4096;                      // 4096
  float* ws_fc   = ws_wrp + 4096;                      // B*N*C
  float* ws_sl   = ws_fc + (size_t)B_*N_*C_;           // 5120
  float* ws_lgt  = ws_sl + B_*K_*D_;                   // B*K*N
  float* ws_red  = ws_lgt + (size_t)B_*K_*N_;          // 80*NC*4
  float* ws_part = ws_red + B_*K_*NC_*4;               // 80*NC*64
  float* ws_pc   = ws_part + (size_t)B_*K_*NC_*64;     // 80*NC*16
  int*   ws_cnt  = (int*)(ws_pc + B_*K_*NC_*16);       // 80
  uint16_t* ws_ge  = (uint16_t*)(ws_cnt + 128);
  uint16_t* ws_fk16 = ws_ge + (size_t)K_*N_*D_;
  uint16_t* ws_fv16 = ws_fk16 + (size_t)B_*N_*D_;
  uint16_t* wsK    = ws_fv16 + (size_t)B_*N_*D_;
  uint16_t* wsV    = wsK + (size_t)B_*K_*N_*D_;

  k_pre<<<59,256,0,stream>>>(mask,noise,mu,lsg, wm,bm,lnkb, wk,wv,lnfb,
                             wq,lnqg,lnqb, wres,bres,lnrg,lnrb,
                             ws_fg,out_fg, ws_bm2,ws_fkb,ws_fvb,ws_qb,ws_br2,
                             ws_wqp,ws_wrp, ws_sl, ws_cnt);
  k_gridemb<<<(K_*N_*32)/256,256,0,stream>>>(wg,bg,ws_fg,(uint32_t*)ws_ge);
  k_featln<<<(B_*N_)/64,256,0,stream>>>(feat,wk,wv,lnfg,ws_fkb,ws_fvb,
                                        featc,lncg,lncb, ws_fk16,ws_fv16,ws_fc);
  k_buildkv<<<dim3(N_/256,K_,B_),256,0,stream>>>(ws_fk16,ws_fv16,ws_ge,lnkg,wm,ws_bm2,wsK,wsV);

  for(int it=0; it<4; it++){
    if(it<3){
      k_logits<false><<<dim3(NC_,B_*K_),256,0,stream>>>(wsK,ws_sl,ws_wqp,ws_qb,ws_lgt,ws_red);
      k_updv<false><<<dim3(NC_,B_*K_),256,0,stream>>>(wsV,ws_lgt,ws_red,ws_fc,ws_part,ws_pc,out_attn,
                                                      ws_sl,wih,whh,bih,bhh,ws_wrp,ws_br2,out_slot,ws_cnt);
    } else {
      k_logits<true><<<dim3(NC_,B_*K_),256,0,stream>>>(wsK,ws_sl,ws_wqp,ws_qb,ws_lgt,ws_red);
      k_updv<true><<<dim3(NC_,B_*K_),256,0,stream>>>(wsV,ws_lgt,ws_red,ws_fc,ws_part,ws_pc,out_attn,
                                                     ws_sl,wih,whh,bih,bhh,ws_wrp,ws_br2,out_slot,ws_cnt);
    }
  }
}

// Round 5
// 323.098 us; speedup vs baseline: 1.6129x; 1.6129x over previous
//
#include <hip/hip_runtime.h>
#include <stdint.h>

#define B_ 16
#define H_ 64
#define W_ 64
#define D_ 64
#define C_ 16
#define K_ 5
#define N_ 4096
#define NC_ 8          // attention n-chunks
#define CS_ 512        // chunk size = N_/NC_
#define EPS 1e-5f

typedef __attribute__((ext_vector_type(8))) short bf16x8;
typedef __attribute__((ext_vector_type(4))) float f32x4;

__device__ __forceinline__ float wsum64(float v){
  #pragma unroll
  for(int o=1;o<64;o<<=1) v += __shfl_xor(v,o,64);
  return v;
}
__device__ __forceinline__ float wmax64(float v){
  #pragma unroll
  for(int o=1;o<64;o<<=1) v = fmaxf(v, __shfl_xor(v,o,64));
  return v;
}
__device__ __forceinline__ float wmin64(float v){
  #pragma unroll
  for(int o=1;o<64;o<<=1) v = fminf(v, __shfl_xor(v,o,64));
  return v;
}
__device__ __forceinline__ uint16_t f2bf(float f){
  uint32_t u = __float_as_uint(f);
  u += 0x7fffu + ((u>>16)&1u);
  return (uint16_t)(u>>16);
}
__device__ __forceinline__ void bf8_to_f(uint4 u, float* x){
  x[0]=__uint_as_float(u.x<<16); x[1]=__uint_as_float(u.x&0xffff0000u);
  x[2]=__uint_as_float(u.y<<16); x[3]=__uint_as_float(u.y&0xffff0000u);
  x[4]=__uint_as_float(u.z<<16); x[5]=__uint_as_float(u.z&0xffff0000u);
  x[6]=__uint_as_float(u.w<<16); x[7]=__uint_as_float(u.w&0xffff0000u);
}

// k_pre: fgpos (bid 0-4) + folded biases (5,6) + wqpT/wrpT (7-38)
// + transposed GRU weights (39-134) + slot init (135-154)
__global__ __launch_bounds__(256) void k_pre(
    const float* __restrict__ mask, const float* __restrict__ noise,
    const float* __restrict__ mu, const float* __restrict__ lsg,
    const float* __restrict__ wm, const float* __restrict__ bm, const float* __restrict__ lnkb,
    const float* __restrict__ wk, const float* __restrict__ wv, const float* __restrict__ lnfb,
    const float* __restrict__ wq, const float* __restrict__ lnqg, const float* __restrict__ lnqb,
    const float* __restrict__ wres, const float* __restrict__ bres,
    const float* __restrict__ lnrg, const float* __restrict__ lnrb,
    const float* __restrict__ wih, const float* __restrict__ whh,
    float* __restrict__ ws_fg, float* __restrict__ out_fg,
    float* __restrict__ bm2, float* __restrict__ fkb, float* __restrict__ fvb,
    float* __restrict__ qb, float* __restrict__ br2,
    float* __restrict__ wqpT, float* __restrict__ wrpT, float* __restrict__ gw,
    float* __restrict__ slot){
  int bid=blockIdx.x, tid=threadIdx.x;
  if(bid<5){
    int k=bid;
    float sm=0.f, sx=0.f, sy=0.f;
    for(int p=tid; p<H_*W_; p+=256){
      int i=p>>6, j=p&63;
      float m = mask[k*H_*W_ + p];
      float x = -1.f + (2.f/63.f)*j;
      float y = -1.f + (2.f/63.f)*i;
      sm+=m; sx+=m*x; sy+=m*y;
    }
    __shared__ float r0[4], r1[4], r2[4];
    int wid=tid>>6, lane=tid&63;
    sm=wsum64(sm); sx=wsum64(sx); sy=wsum64(sy);
    if(lane==0){ r0[wid]=sm; r1[wid]=sx; r2[wid]=sy; }
    __syncthreads();
    if(tid==0){
      float tm=r0[0]+r0[1]+r0[2]+r0[3];
      float tx=r1[0]+r1[1]+r1[2]+r1[3];
      float ty=r2[0]+r2[1]+r2[2]+r2[3];
      float px = tx/(tm+1e-5f), py = ty/(tm+1e-5f);
      ws_fg[k*2+0]=px; ws_fg[k*2+1]=py;
      for(int b=0;b<B_;b++){ out_fg[(b*K_+k)*2+0]=px; out_fg[(b*K_+k)*2+1]=py; }
    }
  } else if(bid==5){
    int sel=tid>>6, o=tid&63; float s=0.f;
    if(sel==0){ s=bm[o]; for(int d=0;d<64;d++) s+=lnkb[d]*wm[o*64+d]; bm2[o]=s; }
    else if(sel==1){ for(int d=0;d<64;d++) s+=lnqb[d]*wq[o*64+d]; qb[o]=0.125f*s; }
    else if(sel==2){ for(int d=0;d<64;d++) s+=lnrb[d]*wres[o*64+d]; br2[o]=s+bres[o]; }
    else { for(int d=0;d<64;d++) s+=lnfb[d]*wk[o*64+d]; fkb[o]=s; }
  } else if(bid==6){
    if(tid<64){ int o=tid; float s=0.f; for(int d=0;d<64;d++) s+=lnfb[d]*wv[o*64+d]; fvb[o]=s; }
  } else if(bid<39){
    int i=(bid-7)*256+tid;
    if(i<4096){ int d=i>>6, o=i&63; wqpT[i]=0.125f*lnqg[d]*wq[o*64+d]; }
    else { int j=i-4096; int d=j>>6, o=j&63; wrpT[j]=lnrg[d]*wres[o*64+d]; }
  } else if(bid<135){
    int i=(bid-39)*256+tid;   // < 24576
    int g6=i>>12, r=i&4095, d=r>>6, o=r&63;
    float v = (g6<3)? wih[(g6*64+o)*64+d] : whh[((g6-3)*64+o)*64+d];
    gw[g6*4096 + d*64 + o] = v;
  } else {
    int i=(bid-135)*256+tid;
    if(i<B_*K_*D_){ int d=i&63; slot[i]=mu[d]+expf(lsg[d])*noise[i]; }
  }
}

// feat LN-fold + fk/fv = (dfrs)@(g.w).T + bias (MFMA, bf16 out) ; + color LN
__global__ __launch_bounds__(256) void k_featln(const float* __restrict__ feat,
    const float* __restrict__ wk, const float* __restrict__ wv, const float* __restrict__ gf,
    const float* __restrict__ fkb, const float* __restrict__ fvb,
    const float* __restrict__ fc, const float* __restrict__ gc, const float* __restrict__ bc,
    uint16_t* __restrict__ fko, uint16_t* __restrict__ fvo, float* __restrict__ fcn){
  int tid=threadIdx.x, wid=tid>>6, lane=tid&63;
  int q=lane>>4, c=lane&15;
  size_t row = (size_t)blockIdx.x*64 + wid*16 + c;
  const float* xp = feat + row*64;
  float x[16];
  *(float4*)&x[0]  = *(const float4*)(xp + q*8);
  *(float4*)&x[4]  = *(const float4*)(xp + q*8 + 4);
  *(float4*)&x[8]  = *(const float4*)(xp + 32 + q*8);
  *(float4*)&x[12] = *(const float4*)(xp + 36 + q*8);
  float s=0.f;
  #pragma unroll
  for(int i=0;i<16;i++) s+=x[i];
  s += __shfl_xor(s,16,64); s += __shfl_xor(s,32,64);
  float mean = s*(1.f/64.f);
  float v=0.f;
  #pragma unroll
  for(int i=0;i<16;i++){ float d=x[i]-mean; v+=d*d; }
  v += __shfl_xor(v,16,64); v += __shfl_xor(v,32,64);
  float rs = rsqrtf(v*(1.f/64.f)+EPS);
  float gl[16];
  *(float4*)&gl[0]  = *(const float4*)(gf + q*8);
  *(float4*)&gl[4]  = *(const float4*)(gf + q*8 + 4);
  *(float4*)&gl[8]  = *(const float4*)(gf + 32 + q*8);
  *(float4*)&gl[12] = *(const float4*)(gf + 36 + q*8);
  bf16x8 A0, A1;
  #pragma unroll
  for(int j=0;j<8;j++){
    A0[j] = (short)f2bf((x[j]  -mean)*rs);
    A1[j] = (short)f2bf((x[8+j]-mean)*rs);
  }
  #pragma unroll
  for(int mat=0;mat<2;mat++){
    const float* w = mat? wv : wk;
    const float* fb = mat? fvb : fkb;
    uint16_t* o = (mat? fvo : fko) + row*64;
    #pragma unroll
    for(int ot=0; ot<4; ot++){
      const float* wp = w + (size_t)(ot*16+c)*64 + q*8;
      bf16x8 W0, W1;
      #pragma unroll
      for(int j=0;j<8;j++){ W0[j]=(short)f2bf(wp[j]*gl[j]); W1[j]=(short)f2bf(wp[32+j]*gl[8+j]); }
      float4 bq = *(const float4*)(fb + ot*16 + q*4);
      f32x4 acc = {bq.x,bq.y,bq.z,bq.w};
      acc = __builtin_amdgcn_mfma_f32_16x16x32_bf16(W0, A0, acc, 0,0,0);
      acc = __builtin_amdgcn_mfma_f32_16x16x32_bf16(W1, A1, acc, 0,0,0);
      uint2 u;
      u.x = (uint32_t)f2bf(acc[0]) | ((uint32_t)f2bf(acc[1])<<16);
      u.y = (uint32_t)f2bf(acc[2]) | ((uint32_t)f2bf(acc[3])<<16);
      *(uint2*)(o + ot*16 + q*4) = u;
    }
  }
  // color LN (C=16), 64 rows per block
  int r16=tid>>4, cc=tid&15;
  #pragma unroll
  for(int i=0;i<4;i++){
    size_t row2 = (size_t)blockIdx.x*64 + i*16 + r16;
    float xv = fc[row2*16+cc];
    float ss=xv;
    #pragma unroll
    for(int o=1;o<16;o<<=1) ss += __shfl_xor(ss,o,16);
    float m2 = ss*(1.f/16.f);
    float df = xv-m2;
    float v2 = df*df;
    #pragma unroll
    for(int o=1;o<16;o<<=1) v2 += __shfl_xor(v2,o,16);
    fcn[row2*16+cc] = df*rsqrtf(v2*(1.f/16.f)+EPS)*gc[cc] + bc[cc];
  }
}

// K/V = LN-fold(f{k,v}+ge)@(g.wm).T + bm2 -> bf16. MFMA; ge computed inline.
__global__ __launch_bounds__(256) void k_buildkv(const uint16_t* __restrict__ fk,
    const uint16_t* __restrict__ fv, const float* __restrict__ ws_fg,
    const float* __restrict__ wg, const float* __restrict__ bg,
    const float* __restrict__ gkv, const float* __restrict__ wm, const float* __restrict__ bm2,
    uint16_t* __restrict__ Kw, uint16_t* __restrict__ Vw){
  int tid=threadIdx.x, wid=tid>>6, lane=tid&63;
  int q=lane>>4, c=lane&15;
  int k = blockIdx.y, b = blockIdx.z;
  float fgx = ws_fg[k*2+0], fgy = ws_fg[k*2+1];
  // per-lane grid-embed weights for its 16 channels
  float wgx[16], wgy[16], bgv[16];
  #pragma unroll
  for(int j=0;j<16;j++){
    int d = (j<8)? (q*8+j) : (32+q*8+j-8);
    float4 w4 = *(const float4*)(wg + d*4);
    wgx[j]=w4.x-w4.z; wgy[j]=w4.y-w4.w;
  }
  *(float4*)&bgv[0]  = *(const float4*)(bg + q*8);
  *(float4*)&bgv[4]  = *(const float4*)(bg + q*8 + 4);
  *(float4*)&bgv[8]  = *(const float4*)(bg + 32 + q*8);
  *(float4*)&bgv[12] = *(const float4*)(bg + 36 + q*8);
  float gl[16];
  *(float4*)&gl[0]  = *(const float4*)(gkv + q*8);
  *(float4*)&gl[4]  = *(const float4*)(gkv + q*8 + 4);
  *(float4*)&gl[8]  = *(const float4*)(gkv + 32 + q*8);
  *(float4*)&gl[12] = *(const float4*)(gkv + 36 + q*8);
  bf16x8 Wf[4][2];
  #pragma unroll
  for(int ot=0;ot<4;ot++){
    const float* wp = wm + (size_t)(ot*16+c)*64 + q*8;
    #pragma unroll
    for(int j=0;j<8;j++){ Wf[ot][0][j]=(short)f2bf(wp[j]*gl[j]); Wf[ot][1][j]=(short)f2bf(wp[32+j]*gl[8+j]); }
  }
  float bmv[4][4];
  #pragma unroll
  for(int ot=0;ot<4;ot++) *(float4*)&bmv[ot][0] = *(const float4*)(bm2 + ot*16 + q*4);

  for(int t=0;t<4;t++){
    int n = blockIdx.x*256 + t*64 + wid*16 + c;
    float rx = (-1.f + (2.f/63.f)*(n&63)) - fgx;
    float ry = (-1.f + (2.f/63.f)*(n>>6)) - fgy;
    float ga[16];
    #pragma unroll
    for(int j=0;j<16;j++) ga[j] = fmaf(rx,wgx[j], fmaf(ry,wgy[j], bgv[j]));
    #pragma unroll
    for(int mat=0;mat<2;mat++){
      const uint16_t* fp = (mat? fv : fk) + ((size_t)b*N_ + n)*64;
      float x[16];
      bf8_to_f(*(const uint4*)(fp + q*8), &x[0]);
      bf8_to_f(*(const uint4*)(fp + 32 + q*8), &x[8]);
      #pragma unroll
      for(int i=0;i<16;i++) x[i]+=ga[i];
      float s=0.f;
      #pragma unroll
      for(int i=0;i<16;i++) s+=x[i];
      s += __shfl_xor(s,16,64); s += __shfl_xor(s,32,64);
      float mean = s*(1.f/64.f);
      float v=0.f;
      #pragma unroll
      for(int i=0;i<16;i++){ float d=x[i]-mean; v+=d*d; }
      v += __shfl_xor(v,16,64); v += __shfl_xor(v,32,64);
      float rs = rsqrtf(v*(1.f/64.f)+EPS);
      bf16x8 A0, A1;
      #pragma unroll
      for(int j=0;j<8;j++){
        A0[j] = (short)f2bf((x[j]  -mean)*rs);
        A1[j] = (short)f2bf((x[8+j]-mean)*rs);
      }
      uint16_t* outb = (mat? Vw : Kw) + (((size_t)(b*K_+k))*N_)*64;
      #pragma unroll
      for(int ot=0; ot<4; ot++){
        f32x4 acc = {bmv[ot][0],bmv[ot][1],bmv[ot][2],bmv[ot][3]};
        acc = __builtin_amdgcn_mfma_f32_16x16x32_bf16(Wf[ot][0], A0, acc, 0,0,0);
        acc = __builtin_amdgcn_mfma_f32_16x16x32_bf16(Wf[ot][1], A1, acc, 0,0,0);
        uint2 u;
        u.x = (uint32_t)f2bf(acc[0]) | ((uint32_t)f2bf(acc[1])<<16);
        u.y = (uint32_t)f2bf(acc[2]) | ((uint32_t)f2bf(acc[3])<<16);
        *(uint2*)(outb + (size_t)n*64 + ot*16 + q*4) = u;
      }
    }
  }
}

// logits chunk; wave 0 optionally recomputes GRU (redundant per chunk) then q.
template<bool GRU, bool FINAL>
__global__ __launch_bounds__(256) void k_logits(const uint16_t* __restrict__ Kw,
    const float* __restrict__ slot_prev, float* __restrict__ slot_cur,
    const float* __restrict__ part, const float* __restrict__ gw,
    const float* __restrict__ bih, const float* __restrict__ bhh,
    const float* __restrict__ wrpT, const float* __restrict__ br2,
    const float* __restrict__ wqpT, const float* __restrict__ qb,
    float* __restrict__ lgt, float* __restrict__ red){
  __shared__ float qs[64];
  __shared__ float rm[4], rs_[4], rn[4];
  int chunk=blockIdx.x, bk=blockIdx.y;
  int tid=threadIdx.x, wid=tid>>6, lane=tid&63;
  if(wid==0){
    float cur;
    if(GRU){
      float x=0.f;
      #pragma unroll
      for(int cch=0;cch<NC_;cch++) x += part[((size_t)bk*NC_+cch)*64+lane];
      float hp = slot_prev[bk*64+lane];
      float gir=bih[lane], giz=bih[64+lane], gin=bih[128+lane];
      float ghr=bhh[lane], ghz=bhh[64+lane], ghn=bhh[128+lane];
      #pragma unroll 8
      for(int d=0;d<64;d++){
        float xd=__shfl(x,d,64), hd=__shfl(hp,d,64);
        gir = fmaf(xd, gw[d*64+lane], gir);
        giz = fmaf(xd, gw[4096+d*64+lane], giz);
        gin = fmaf(xd, gw[8192+d*64+lane], gin);
        ghr = fmaf(hd, gw[12288+d*64+lane], ghr);
        ghz = fmaf(hd, gw[16384+d*64+lane], ghz);
        ghn = fmaf(hd, gw[20480+d*64+lane], ghn);
      }
      float r=1.f/(1.f+__expf(-(gir+ghr)));
      float z=1.f/(1.f+__expf(-(giz+ghz)));
      float nn=tanhf(gin+r*ghn);
      float sp=(1.f-z)*nn+z*hp;
      float m=wsum64(sp)*(1.f/64.f); float df=sp-m;
      float var=wsum64(df*df)*(1.f/64.f);
      float dr=df*rsqrtf(var+EPS);
      float a=br2[lane]+hp;
      #pragma unroll 8
      for(int d=0;d<64;d++) a = fmaf(__shfl(dr,d,64), wrpT[d*64+lane], a);
      cur = a;
      if(chunk==0) slot_cur[bk*64+lane]=a;
    } else {
      cur = slot_prev[bk*64+lane];
    }
    float m=wsum64(cur)*(1.f/64.f); float df=cur-m;
    float var=wsum64(df*df)*(1.f/64.f);
    float dr=df*rsqrtf(var+EPS);
    float a=qb[lane];
    #pragma unroll 8
    for(int d=0;d<64;d++) a = fmaf(__shfl(dr,d,64), wqpT[d*64+lane], a);
    qs[lane]=a;
  }
  __syncthreads();
  const uint4* Kb = (const uint4*)(Kw + (size_t)bk*N_*64) + (size_t)chunk*CS_*8;
  float l[2];
  #pragma unroll
  for(int i=0;i<2;i++){
    int n = tid + i*256;
    float a=0.f;
    #pragma unroll
    for(int j=0;j<8;j++){
      uint4 u = Kb[(size_t)n*8+j];
      a += __uint_as_float(u.x<<16)          * qs[j*8+0]
         + __uint_as_float(u.x&0xffff0000u)  * qs[j*8+1]
         + __uint_as_float(u.y<<16)          * qs[j*8+2]
         + __uint_as_float(u.y&0xffff0000u)  * qs[j*8+3]
         + __uint_as_float(u.z<<16)          * qs[j*8+4]
         + __uint_as_float(u.z&0xffff0000u)  * qs[j*8+5]
         + __uint_as_float(u.w<<16)          * qs[j*8+6]
         + __uint_as_float(u.w&0xffff0000u)  * qs[j*8+7];
    }
    l[i]=a;
    lgt[(size_t)bk*N_ + chunk*CS_ + n] = a;
  }
  float wm_ = wmax64(fmaxf(l[0],l[1]));
  if(lane==0) rm[wid]=wm_;
  if(FINAL){ float mn=wmin64(fminf(l[0],l[1])); if(lane==0) rn[wid]=mn; }
  __syncthreads();
  float m_c = fmaxf(fmaxf(rm[0],rm[1]),fmaxf(rm[2],rm[3]));
  float s = __expf(l[0]-m_c)+__expf(l[1]-m_c);
  s = wsum64(s);
  if(lane==0) rs_[wid]=s;
  __syncthreads();
  if(tid==0){
    float* rp = red + ((size_t)bk*NC_+chunk)*4;
    rp[0]=m_c;
    rp[1]=rs_[0]+rs_[1]+rs_[2]+rs_[3];
    if(FINAL) rp[2]=fminf(fminf(rn[0],rn[1]),fminf(rn[2],rn[3]));
  }
}

// chunk p + partial upd=p@V (+FINAL: p@featc, out_attn)
template<bool FINAL>
__global__ __launch_bounds__(256) void k_updv(const uint16_t* __restrict__ Vw,
    const float* __restrict__ lgt, const float* __restrict__ red,
    const float* __restrict__ featc,
    float* __restrict__ part, float* __restrict__ partc, float* __restrict__ out_attn){
  __shared__ float ps[CS_];
  __shared__ float pw[4][64];
  __shared__ float pcz[4][16];
  int chunk=blockIdx.x, bk=blockIdx.y, b=bk/K_;
  int tid=threadIdx.x, wid=tid>>6, lane=tid&63, sub=lane>>4, c4=lane&15;
  const float* rp = red + (size_t)bk*NC_*4;
  float M=-1e30f;
  #pragma unroll
  for(int i=0;i<NC_;i++) M = fmaxf(M, rp[i*4]);
  float S=0.f;
  #pragma unroll
  for(int i=0;i<NC_;i++) S += rp[i*4+1]*__expf(rp[i*4]-M);
  float invS = 1.f/S;
  float amin=0.f, dinv=0.f;
  if(FINAL){
    float LMIN=1e30f;
    #pragma unroll
    for(int i=0;i<NC_;i++) LMIN=fminf(LMIN, rp[i*4+2]);
    amin = __expf(LMIN-M)*invS;
    dinv = 1.f/(invS - amin + 1e-5f);
  }
  const float* lp = lgt + (size_t)bk*N_ + chunk*CS_;
  #pragma unroll
  for(int i=0;i<2;i++){
    int n = tid + i*256;
    float p = __expf(lp[n]-M)*invS;
    ps[n]=p;
    if(FINAL) out_attn[(size_t)bk*N_ + chunk*CS_ + n] = (p - amin)*dinv;
  }
  __syncthreads();
  const uint2* Vb = (const uint2*)(Vw + (size_t)bk*N_*64) + (size_t)chunk*CS_*16;
  const float* Fb = featc + ((size_t)b*N_ + chunk*CS_)*16;
  float a0=0.f,a1=0.f,a2=0.f,a3=0.f,ac=0.f;
  for(int t=0;t<32;t++){
    int n = wid*128 + t*4 + sub;
    float p = ps[n];
    uint2 u = Vb[(size_t)n*16 + c4];
    a0 += p*__uint_as_float(u.x<<16);
    a1 += p*__uint_as_float(u.x&0xffff0000u);
    a2 += p*__uint_as_float(u.y<<16);
    a3 += p*__uint_as_float(u.y&0xffff0000u);
    if(FINAL) ac += p*Fb[(size_t)n*16 + c4];
  }
  a0+=__shfl_xor(a0,16,64); a0+=__shfl_xor(a0,32,64);
  a1+=__shfl_xor(a1,16,64); a1+=__shfl_xor(a1,32,64);
  a2+=__shfl_xor(a2,16,64); a2+=__shfl_xor(a2,32,64);
  a3+=__shfl_xor(a3,16,64); a3+=__shfl_xor(a3,32,64);
  if(FINAL){ ac+=__shfl_xor(ac,16,64); ac+=__shfl_xor(ac,32,64); }
  if(lane<16){
    pw[wid][lane*4+0]=a0; pw[wid][lane*4+1]=a1;
    pw[wid][lane*4+2]=a2; pw[wid][lane*4+3]=a3;
    if(FINAL) pcz[wid][lane]=ac;
  }
  __syncthreads();
  if(tid<64){
    part[((size_t)bk*NC_+chunk)*64 + tid] = pw[0][tid]+pw[1][tid]+pw[2][tid]+pw[3][tid];
  }
  if(FINAL && tid<16){
    partc[((size_t)bk*NC_+chunk)*16 + tid] = pcz[0][tid]+pcz[1][tid]+pcz[2][tid]+pcz[3][tid];
  }
}

// final: out_slot = [slot_3, sum of color partials]
__global__ __launch_bounds__(64) void k_final(const float* __restrict__ slot,
    const float* __restrict__ partc, float* __restrict__ out_slot){
  int bk=blockIdx.x, lane=threadIdx.x;
  out_slot[bk*80+lane]=slot[bk*64+lane];
  if(lane<16){
    float s=0.f;
    #pragma unroll
    for(int cch=0;cch<NC_;cch++) s += partc[((size_t)bk*NC_+cch)*16+lane];
    out_slot[bk*80+64+lane]=s;
  }
}

extern "C" void kernel_launch(void* const* d_in, const int* in_sizes, int n_in,
                              void* d_out, int out_size, void* d_ws, size_t ws_size,
                              hipStream_t stream){
  (void)in_sizes; (void)n_in; (void)out_size; (void)ws_size;
  const float* feat = (const float*)d_in[0];
  const float* featc= (const float*)d_in[1];
  const float* mask = (const float*)d_in[2];
  const float* noise= (const float*)d_in[3];
  const float* mu   = (const float*)d_in[4];
  const float* lsg  = (const float*)d_in[5];
  const float* wg   = (const float*)d_in[6];
  const float* bg   = (const float*)d_in[7];
  const float* wk   = (const float*)d_in[8];
  const float* wv   = (const float*)d_in[9];
  const float* lnkg = (const float*)d_in[10];
  const float* lnkb = (const float*)d_in[11];
  const float* wm   = (const float*)d_in[12];
  const float* bm   = (const float*)d_in[13];
  const float* lnqg = (const float*)d_in[14];
  const float* lnqb = (const float*)d_in[15];
  const float* wq   = (const float*)d_in[16];
  const float* wih  = (const float*)d_in[17];
  const float* whh  = (const float*)d_in[18];
  const float* bih  = (const float*)d_in[19];
  const float* bhh  = (const float*)d_in[20];
  const float* lnfg = (const float*)d_in[21];
  const float* lnfb = (const float*)d_in[22];
  const float* lncg = (const float*)d_in[23];
  const float* lncb = (const float*)d_in[24];
  const float* lnrg = (const float*)d_in[25];
  const float* lnrb = (const float*)d_in[26];
  const float* wres = (const float*)d_in[27];
  const float* bres = (const float*)d_in[28];

  float* out = (float*)d_out;
  float* out_slot = out;          // (B,K,80)
  float* out_fg   = out + 6400;   // (B,K,2)
  float* out_attn = out + 6560;   // (B,K,N)

  float* wsf     = (float*)d_ws;
  float* ws_fg   = wsf;                                // 16
  float* ws_bm2  = wsf + 16;                           // 64
  float* ws_fkb  = ws_bm2 + 64;                        // 64
  float* ws_fvb  = ws_fkb + 64;                        // 64
  float* ws_qb   = ws_fvb + 64;                        // 64
  float* ws_br2  = ws_qb + 64;                         // 64
  float* ws_wqpT = ws_br2 + 64;                        // 4096
  float* ws_wrpT = ws_wqpT + 4096;                     // 4096
  float* ws_gw   = ws_wrpT + 4096;                     // 24576
  float* ws_fc   = ws_gw + 24576;                      // B*N*C
  float* ws_sl0  = ws_fc + (size_t)B_*N_*C_;           // 5120
  float* ws_sl1  = ws_sl0 + B_*K_*D_;                  // 5120
  float* ws_lgt  = ws_sl1 + B_*K_*D_;                  // B*K*N
  float* ws_red  = ws_lgt + (size_t)B_*K_*N_;          // 80*NC*4
  float* ws_part = ws_red + B_*K_*NC_*4;               // 80*NC*64
  float* ws_pc   = ws_part + (size_t)B_*K_*NC_*64;     // 80*NC*16
  uint16_t* ws_fk16 = (uint16_t*)(ws_pc + B_*K_*NC_*16);
  uint16_t* ws_fv16 = ws_fk16 + (size_t)B_*N_*D_;
  uint16_t* wsK    = ws_fv16 + (size_t)B_*N_*D_;
  uint16_t* wsV    = wsK + (size_t)B_*K_*N_*D_;

  k_pre<<<155,256,0,stream>>>(mask,noise,mu,lsg, wm,bm,lnkb, wk,wv,lnfb,
                              wq,lnqg,lnqb, wres,bres,lnrg,lnrb, wih,whh,
                              ws_fg,out_fg, ws_bm2,ws_fkb,ws_fvb,ws_qb,ws_br2,
                              ws_wqpT,ws_wrpT,ws_gw, ws_sl0);
  k_featln<<<(B_*N_)/64,256,0,stream>>>(feat,wk,wv,lnfg,ws_fkb,ws_fvb,
                                        featc,lncg,lncb, ws_fk16,ws_fv16,ws_fc);
  k_buildkv<<<dim3(N_/256,K_,B_),256,0,stream>>>(ws_fk16,ws_fv16,ws_fg,wg,bg,
                                                 lnkg,wm,ws_bm2,wsK,wsV);

  dim3 agrid(NC_,B_*K_);
  // it 0: slot0 -> q
  k_logits<false,false><<<agrid,256,0,stream>>>(wsK, ws_sl0, ws_sl0, ws_part, ws_gw,
      bih,bhh, ws_wrpT,ws_br2, ws_wqpT,ws_qb, ws_lgt, ws_red);
  k_updv<false><<<agrid,256,0,stream>>>(wsV,ws_lgt,ws_red,ws_fc,ws_part,ws_pc,out_attn);
  // it 1: GRU(slot0,upd0)=slot1
  k_logits<true,false><<<agrid,256,0,stream>>>(wsK, ws_sl0, ws_sl1, ws_part, ws_gw,
      bih,bhh, ws_wrpT,ws_br2, ws_wqpT,ws_qb, ws_lgt, ws_red);
  k_updv<false><<<agrid,256,0,stream>>>(wsV,ws_lgt,ws_red,ws_fc,ws_part,ws_pc,out_attn);
  // it 2: GRU(slot1,upd1)=slot2
  k_logits<true,false><<<agrid,256,0,stream>>>(wsK, ws_sl1, ws_sl0, ws_part, ws_gw,
      bih,bhh, ws_wrpT,ws_br2, ws_wqpT,ws_qb, ws_lgt, ws_red);
  k_updv<false><<<agrid,256,0,stream>>>(wsV,ws_lgt,ws_red,ws_fc,ws_part,ws_pc,out_attn);
  // it 3 (final): GRU(slot2,upd2)=slot3
  k_logits<true,true><<<agrid,256,0,stream>>>(wsK, ws_sl0, ws_sl1, ws_part, ws_gw,
      bih,bhh, ws_wrpT,ws_br2, ws_wqpT,ws_qb, ws_lgt, ws_red);
  k_updv<true><<<agrid,256,0,stream>>>(wsV,ws_lgt,ws_red,ws_fc,ws_part,ws_pc,out_attn);
  k_final<<<B_*K_,64,0,stream>>>(ws_sl1, ws_pc, out_slot);
}

// Round 6
// 259.663 us; speedup vs baseline: 2.0069x; 1.2443x over previous
//
#include <hip/hip_runtime.h>
#include <stdint.h>

#define B_ 16
#define H_ 64
#define W_ 64
#define D_ 64
#define C_ 16
#define K_ 5
#define N_ 4096
#define NC_ 8          // attention n-chunks
#define CS_ 512        // chunk size = N_/NC_
#define EPS 1e-5f

typedef __attribute__((ext_vector_type(8))) short bf16x8;
typedef __attribute__((ext_vector_type(4))) float f32x4;

__device__ __forceinline__ float wsum64(float v){
  #pragma unroll
  for(int o=1;o<64;o<<=1) v += __shfl_xor(v,o,64);
  return v;
}
__device__ __forceinline__ float wmax64(float v){
  #pragma unroll
  for(int o=1;o<64;o<<=1) v = fmaxf(v, __shfl_xor(v,o,64));
  return v;
}
__device__ __forceinline__ float wmin64(float v){
  #pragma unroll
  for(int o=1;o<64;o<<=1) v = fminf(v, __shfl_xor(v,o,64));
  return v;
}
__device__ __forceinline__ uint16_t f2bf(float f){
  uint32_t u = __float_as_uint(f);
  u += 0x7fffu + ((u>>16)&1u);
  return (uint16_t)(u>>16);
}

// k_pre: fgpos (0-4) + folded biases (5) + fvb/wgx/wgy/gscal (6)
// + wqpT/wrpT/wvT/wmT (7-70) + gw (71-166) + slot init (167-186)
__global__ __launch_bounds__(256) void k_pre(
    const float* __restrict__ mask, const float* __restrict__ noise,
    const float* __restrict__ mu, const float* __restrict__ lsg,
    const float* __restrict__ wm, const float* __restrict__ bm, const float* __restrict__ lnkb,
    const float* __restrict__ wk, const float* __restrict__ wv, const float* __restrict__ lnfb,
    const float* __restrict__ wq, const float* __restrict__ lnqg, const float* __restrict__ lnqb,
    const float* __restrict__ wres, const float* __restrict__ bres,
    const float* __restrict__ lnrg, const float* __restrict__ lnrb,
    const float* __restrict__ wih, const float* __restrict__ whh,
    const float* __restrict__ wg, const float* __restrict__ bg,
    float* __restrict__ ws_fg, float* __restrict__ out_fg,
    float* __restrict__ bm2, float* __restrict__ fkb, float* __restrict__ fvb,
    float* __restrict__ qb, float* __restrict__ br2,
    float* __restrict__ wgx, float* __restrict__ wgy, float* __restrict__ gscal,
    float* __restrict__ wqpT, float* __restrict__ wrpT,
    float* __restrict__ wvT, float* __restrict__ wmT,
    float* __restrict__ gw, float* __restrict__ slot){
  int bid=blockIdx.x, tid=threadIdx.x;
  if(bid<5){
    int k=bid;
    float sm=0.f, sx=0.f, sy=0.f;
    for(int p=tid; p<H_*W_; p+=256){
      int i=p>>6, j=p&63;
      float m = mask[k*H_*W_ + p];
      float x = -1.f + (2.f/63.f)*j;
      float y = -1.f + (2.f/63.f)*i;
      sm+=m; sx+=m*x; sy+=m*y;
    }
    __shared__ float r0[4], r1[4], r2[4];
    int wid=tid>>6, lane=tid&63;
    sm=wsum64(sm); sx=wsum64(sx); sy=wsum64(sy);
    if(lane==0){ r0[wid]=sm; r1[wid]=sx; r2[wid]=sy; }
    __syncthreads();
    if(tid==0){
      float tm=r0[0]+r0[1]+r0[2]+r0[3];
      float tx=r1[0]+r1[1]+r1[2]+r1[3];
      float ty=r2[0]+r2[1]+r2[2]+r2[3];
      float px = tx/(tm+1e-5f), py = ty/(tm+1e-5f);
      ws_fg[k*2+0]=px; ws_fg[k*2+1]=py;
      for(int b=0;b<B_;b++){ out_fg[(b*K_+k)*2+0]=px; out_fg[(b*K_+k)*2+1]=py; }
    }
  } else if(bid==5){
    int sel=tid>>6, o=tid&63; float s=0.f;
    if(sel==0){ s=bm[o]; for(int d=0;d<64;d++) s+=lnkb[d]*wm[o*64+d]; bm2[o]=s; }
    else if(sel==1){ for(int d=0;d<64;d++) s+=lnqb[d]*wq[o*64+d]; qb[o]=0.125f*s; }
    else if(sel==2){ for(int d=0;d<64;d++) s+=lnrb[d]*wres[o*64+d]; br2[o]=s+bres[o]; }
    else { for(int d=0;d<64;d++) s+=lnfb[d]*wk[o*64+d]; fkb[o]=s; }
  } else if(bid==6){
    int wv4=tid>>6, l=tid&63;
    if(wv4==0){ float s=0.f; for(int d=0;d<64;d++) s+=lnfb[d]*wv[l*64+d]; fvb[l]=s; }
    else if(wv4==1){
      float4 w4 = *(const float4*)(wg + l*4);
      wgx[l]=w4.x-w4.z; wgy[l]=w4.y-w4.w;
    } else if(wv4==2){
      float4 w4 = *(const float4*)(wg + l*4);
      float wx=w4.x-w4.z, wy=w4.y-w4.w, bl=bg[l];
      float t;
      t=wsum64(wx);    if(l==0) gscal[0]=t*(1.f/64.f);
      t=wsum64(wy);    if(l==0) gscal[1]=t*(1.f/64.f);
      t=wsum64(bl);    if(l==0) gscal[2]=t*(1.f/64.f);
      t=wsum64(wx*wx); if(l==0) gscal[3]=t*(1.f/64.f);
      t=wsum64(wy*wy); if(l==0) gscal[4]=t*(1.f/64.f);
      t=wsum64(wx*wy); if(l==0) gscal[5]=t*(2.f/64.f);
      t=wsum64(wx*bl); if(l==0) gscal[6]=t*(2.f/64.f);
      t=wsum64(wy*bl); if(l==0) gscal[7]=t*(2.f/64.f);
      t=wsum64(bl*bl); if(l==0) gscal[8]=t*(1.f/64.f);
    }
  } else if(bid<71){
    int i=(bid-7)*256+tid;           // < 16384
    int a=i>>12, r=i&4095, d=r>>6, o=r&63;
    if(a==0)      wqpT[r]=0.125f*lnqg[d]*wq[o*64+d];
    else if(a==1) wrpT[r]=lnrg[d]*wres[o*64+d];
    else if(a==2) wvT[r]=wv[o*64+d];
    else          wmT[r]=wm[o*64+d];
  } else if(bid<167){
    int i=(bid-71)*256+tid;          // < 24576
    int g6=i>>12, r=i&4095, d=r>>6, o=r&63;
    float v = (g6<3)? wih[(g6*64+o)*64+d] : whh[((g6-3)*64+o)*64+d];
    gw[g6*4096 + d*64 + o] = v;
  } else {
    int i=(bid-167)*256+tid;
    if(i<B_*K_*D_){ int d=i&63; slot[i]=mu[d]+expf(lsg[d])*noise[i]; }
  }
}

// feat LN -> A (bf16); transient MFMA fk/fv rows -> per-row stat float4s; color LN.
__global__ __launch_bounds__(256) void k_featln(const float* __restrict__ feat,
    const float* __restrict__ wk, const float* __restrict__ wv, const float* __restrict__ gf,
    const float* __restrict__ fkb, const float* __restrict__ fvb,
    const float* __restrict__ wgx, const float* __restrict__ wgy, const float* __restrict__ bg,
    const float* __restrict__ fc, const float* __restrict__ gc, const float* __restrict__ bc,
    uint16_t* __restrict__ Aout, float4* __restrict__ kstat, float4* __restrict__ vstat,
    float* __restrict__ fcn){
  int tid=threadIdx.x, wid=tid>>6, lane=tid&63;
  int q=lane>>4, c=lane&15;
  size_t row = (size_t)blockIdx.x*64 + wid*16 + c;
  const float* xp = feat + row*64;
  float x[16];
  *(float4*)&x[0]  = *(const float4*)(xp + q*8);
  *(float4*)&x[4]  = *(const float4*)(xp + q*8 + 4);
  *(float4*)&x[8]  = *(const float4*)(xp + 32 + q*8);
  *(float4*)&x[12] = *(const float4*)(xp + 36 + q*8);
  float s=0.f;
  #pragma unroll
  for(int i=0;i<16;i++) s+=x[i];
  s += __shfl_xor(s,16,64); s += __shfl_xor(s,32,64);
  float mean = s*(1.f/64.f);
  float v=0.f;
  #pragma unroll
  for(int i=0;i<16;i++){ float d=x[i]-mean; v+=d*d; }
  v += __shfl_xor(v,16,64); v += __shfl_xor(v,32,64);
  float rs = rsqrtf(v*(1.f/64.f)+EPS);
  float gl[16];
  *(float4*)&gl[0]  = *(const float4*)(gf + q*8);
  *(float4*)&gl[4]  = *(const float4*)(gf + q*8 + 4);
  *(float4*)&gl[8]  = *(const float4*)(gf + 32 + q*8);
  *(float4*)&gl[12] = *(const float4*)(gf + 36 + q*8);
  bf16x8 A0, A1;
  #pragma unroll
  for(int j=0;j<8;j++){
    A0[j] = (short)f2bf((x[j]  -mean)*rs);
    A1[j] = (short)f2bf((x[8+j]-mean)*rs);
  }
  *(bf16x8*)(Aout + row*64 + q*8) = A0;
  *(bf16x8*)(Aout + row*64 + 32 + q*8) = A1;
  // channel params for stat dots: channels ot*16+q*4+r
  float wgxl[4][4], wgyl[4][4], bgl[4][4];
  #pragma unroll
  for(int ot=0;ot<4;ot++){
    *(float4*)&wgxl[ot][0] = *(const float4*)(wgx + ot*16 + q*4);
    *(float4*)&wgyl[ot][0] = *(const float4*)(wgy + ot*16 + q*4);
    *(float4*)&bgl[ot][0]  = *(const float4*)(bg + ot*16 + q*4);
  }
  #pragma unroll
  for(int mat=0;mat<2;mat++){
    const float* w = mat? wv : wk;
    const float* fb = mat? fvb : fkb;
    float ss=0.f, s2=0.f, dx=0.f, dy=0.f, db=0.f;
    #pragma unroll
    for(int ot=0; ot<4; ot++){
      const float* wp = w + (size_t)(ot*16+c)*64 + q*8;
      bf16x8 W0, W1;
      #pragma unroll
      for(int j=0;j<8;j++){ W0[j]=(short)f2bf(wp[j]*gl[j]); W1[j]=(short)f2bf(wp[32+j]*gl[8+j]); }
      float4 bq = *(const float4*)(fb + ot*16 + q*4);
      f32x4 acc = {bq.x,bq.y,bq.z,bq.w};
      acc = __builtin_amdgcn_mfma_f32_16x16x32_bf16(W0, A0, acc, 0,0,0);
      acc = __builtin_amdgcn_mfma_f32_16x16x32_bf16(W1, A1, acc, 0,0,0);
      #pragma unroll
      for(int r=0;r<4;r++){
        float a=acc[r];
        ss+=a; s2+=a*a;
        dx = fmaf(a, wgxl[ot][r], dx);
        dy = fmaf(a, wgyl[ot][r], dy);
        db = fmaf(a, bgl[ot][r], db);
      }
    }
    ss += __shfl_xor(ss,16,64); ss += __shfl_xor(ss,32,64);
    s2 += __shfl_xor(s2,16,64); s2 += __shfl_xor(s2,32,64);
    dx += __shfl_xor(dx,16,64); dx += __shfl_xor(dx,32,64);
    dy += __shfl_xor(dy,16,64); dy += __shfl_xor(dy,32,64);
    db += __shfl_xor(db,16,64); db += __shfl_xor(db,32,64);
    if(lane<16){
      size_t row2 = (size_t)blockIdx.x*64 + wid*16 + lane;
      float4 st = { ss*(1.f/64.f), s2*(1.f/64.f)+db*(1.f/32.f), dx*(1.f/32.f), dy*(1.f/32.f) };
      (mat? vstat : kstat)[row2] = st;
    }
  }
  // color LN (C=16), 64 rows per block
  int r16=tid>>4, cc=tid&15;
  #pragma unroll
  for(int i=0;i<4;i++){
    size_t row2 = (size_t)blockIdx.x*64 + i*16 + r16;
    float xv = fc[row2*16+cc];
    float sc=xv;
    #pragma unroll
    for(int o=1;o<16;o<<=1) sc += __shfl_xor(sc,o,16);
    float m2 = sc*(1.f/16.f);
    float df = xv-m2;
    float v2 = df*df;
    #pragma unroll
    for(int o=1;o<16;o<<=1) v2 += __shfl_xor(v2,o,16);
    fcn[row2*16+cc] = df*rsqrtf(v2*(1.f/16.f)+EPS)*gc[cc] + bc[cc];
  }
}

// logits chunk via algebraic K; wave0: [GRU from partials] + q/q'/q'' + consts
template<bool GRU, bool FINAL>
__global__ __launch_bounds__(256) void k_logits(const uint16_t* __restrict__ Aw,
    const float4* __restrict__ kstat,
    const float* __restrict__ slot_prev, float* __restrict__ slot_cur,
    const float* __restrict__ part, const float* __restrict__ pscal,
    const float* __restrict__ gw,
    const float* __restrict__ bih, const float* __restrict__ bhh,
    const float* __restrict__ wrpT, const float* __restrict__ br2,
    const float* __restrict__ wqpT, const float* __restrict__ qb,
    const float* __restrict__ wm, const float* __restrict__ wk,
    const float* __restrict__ lnfg, const float* __restrict__ lnkg,
    const float* __restrict__ fkb, const float* __restrict__ bm2, const float* __restrict__ fvb,
    const float* __restrict__ wvT, const float* __restrict__ wmT,
    const float* __restrict__ wgx, const float* __restrict__ wgy, const float* __restrict__ bg,
    const float* __restrict__ gscal, const float* __restrict__ ws_fg,
    float* __restrict__ lgt, float* __restrict__ red){
  __shared__ float qs[64];
  __shared__ float cst[5];
  __shared__ float rm[4], rs_[4], rn[4];
  int chunk=blockIdx.x, bk=blockIdx.y, b=bk/K_, k=bk-b*K_;
  int tid=threadIdx.x, wid=tid>>6, lane=tid&63;
  float mwgx=gscal[0], mwgy=gscal[1], mbg=gscal[2];
  float g1=gscal[3], g2=gscal[4], g3=gscal[5], g4=gscal[6], g5=gscal[7], g6=gscal[8];
  float fgx=ws_fg[k*2+0], fgy=ws_fg[k*2+1];
  if(wid==0){
    float cur;
    if(GRU){
      float sA=0.f, As=0.f, Ax=0.f, Ay=0.f, Am=0.f;
      #pragma unroll
      for(int cch=0;cch<NC_;cch++){
        sA += part[((size_t)bk*NC_+cch)*64+lane];
        const float* pp = pscal + ((size_t)bk*NC_+cch)*4;
        As+=pp[0]; Ax+=pp[1]; Ay+=pp[2]; Am+=pp[3];
      }
      float sAp = lnfg[lane]*sA;
      float fvs = fvb[lane]*As;
      #pragma unroll 8
      for(int d=0;d<64;d++) fvs = fmaf(__shfl(sAp,d,64), wvT[d*64+lane], fvs);
      float zs = fvs + Ax*wgx[lane] + Ay*wgy[lane] + As*bg[lane] - Am;
      float zsp = lnkg[lane]*zs;
      float x = bm2[lane];
      #pragma unroll 8
      for(int d=0;d<64;d++) x = fmaf(__shfl(zsp,d,64), wmT[d*64+lane], x);
      float hp = slot_prev[bk*64+lane];
      float gir=bih[lane], giz=bih[64+lane], gin=bih[128+lane];
      float ghr=bhh[lane], ghz=bhh[64+lane], ghn=bhh[128+lane];
      #pragma unroll 8
      for(int d=0;d<64;d++){
        float xd=__shfl(x,d,64), hd=__shfl(hp,d,64);
        gir = fmaf(xd, gw[d*64+lane], gir);
        giz = fmaf(xd, gw[4096+d*64+lane], giz);
        gin = fmaf(xd, gw[8192+d*64+lane], gin);
        ghr = fmaf(hd, gw[12288+d*64+lane], ghr);
        ghz = fmaf(hd, gw[16384+d*64+lane], ghz);
        ghn = fmaf(hd, gw[20480+d*64+lane], ghn);
      }
      float r=1.f/(1.f+__expf(-(gir+ghr)));
      float z=1.f/(1.f+__expf(-(giz+ghz)));
      float nn=tanhf(gin+r*ghn);
      float sp=(1.f-z)*nn+z*hp;
      float m=wsum64(sp)*(1.f/64.f); float df=sp-m;
      float var=wsum64(df*df)*(1.f/64.f);
      float dr=df*rsqrtf(var+EPS);
      float a=br2[lane]+hp;
      #pragma unroll 8
      for(int d=0;d<64;d++) a = fmaf(__shfl(dr,d,64), wrpT[d*64+lane], a);
      cur = a;
      if(chunk==0) slot_cur[bk*64+lane]=a;
    } else {
      cur = slot_prev[bk*64+lane];
    }
    float m=wsum64(cur)*(1.f/64.f); float df=cur-m;
    float var=wsum64(df*df)*(1.f/64.f);
    float dr=df*rsqrtf(var+EPS);
    float qv=qb[lane];
    #pragma unroll 8
    for(int d=0;d<64;d++) qv = fmaf(__shfl(dr,d,64), wqpT[d*64+lane], qv);
    float qp=0.f;
    #pragma unroll 8
    for(int o=0;o<64;o++) qp = fmaf(__shfl(qv,o,64), wm[o*64+lane], qp);
    qp *= lnkg[lane];
    float qpp=0.f;
    #pragma unroll 8
    for(int o=0;o<64;o++) qpp = fmaf(__shfl(qp,o,64), wk[o*64+lane], qpp);
    qpp *= lnfg[lane];
    qs[lane]=qpp;
    float s1 = wsum64(qp);
    float c1 = wsum64(qp*wgx[lane]);
    float c2 = wsum64(qp*wgy[lane]);
    float c3 = wsum64(qp*(bg[lane]+fkb[lane]));
    float c4 = wsum64(qv*bm2[lane]);
    if(lane==0){
      cst[0]=c1-s1*mwgx; cst[1]=c2-s1*mwgy; cst[2]=c3-s1*mbg; cst[3]=s1; cst[4]=c4;
    }
  }
  __syncthreads();
  float CX=cst[0], CY=cst[1], C0=cst[2], S1=cst[3], C4=cst[4];
  const uint4* Ab = (const uint4*)Aw + (size_t)b*N_*8 + (size_t)chunk*CS_*8;
  const float4* ks = kstat + (size_t)b*N_ + chunk*CS_;
  float l[2];
  #pragma unroll
  for(int i=0;i<2;i++){
    int nl = tid + i*256;
    int n = chunk*CS_ + nl;
    float dot=0.f;
    #pragma unroll
    for(int j=0;j<8;j++){
      uint4 u = Ab[(size_t)nl*8+j];
      dot += __uint_as_float(u.x<<16)          * qs[j*8+0]
           + __uint_as_float(u.x&0xffff0000u)  * qs[j*8+1]
           + __uint_as_float(u.y<<16)          * qs[j*8+2]
           + __uint_as_float(u.y&0xffff0000u)  * qs[j*8+3]
           + __uint_as_float(u.z<<16)          * qs[j*8+4]
           + __uint_as_float(u.z&0xffff0000u)  * qs[j*8+5]
           + __uint_as_float(u.w<<16)          * qs[j*8+6]
           + __uint_as_float(u.w&0xffff0000u)  * qs[j*8+7];
    }
    float4 st = ks[nl];
    float rx = (-1.f + (2.f/63.f)*(n&63)) - fgx;
    float ry = (-1.f + (2.f/63.f)*(n>>6)) - fgy;
    float mu = st.x + rx*mwgx + ry*mwgy + mbg;
    float var = st.y + rx*st.z + ry*st.w
              + (g1*rx*rx + g2*ry*ry + g3*rx*ry + g4*rx + g5*ry + g6) - mu*mu;
    float rsn = rsqrtf(var + EPS);
    float a = rsn*(dot + rx*CX + ry*CY + C0 - S1*st.x) + C4;
    l[i]=a;
    lgt[(size_t)bk*N_ + n] = a;
  }
  float wm_ = wmax64(fmaxf(l[0],l[1]));
  if(lane==0) rm[wid]=wm_;
  if(FINAL){ float mn=wmin64(fminf(l[0],l[1])); if(lane==0) rn[wid]=mn; }
  __syncthreads();
  float m_c = fmaxf(fmaxf(rm[0],rm[1]),fmaxf(rm[2],rm[3]));
  float s = __expf(l[0]-m_c)+__expf(l[1]-m_c);
  s = wsum64(s);
  if(lane==0) rs_[wid]=s;
  __syncthreads();
  if(tid==0){
    float* rp = red + ((size_t)bk*NC_+chunk)*4;
    rp[0]=m_c;
    rp[1]=rs_[0]+rs_[1]+rs_[2]+rs_[3];
    if(FINAL) rp[2]=fminf(fminf(rn[0],rn[1]),fminf(rn[2],rn[3]));
  }
}

// chunk: p, w=p*rs_v; partial zsum-vec = sum w*A, scalars; (+FINAL: color, out_attn)
template<bool FINAL>
__global__ __launch_bounds__(256) void k_updv(const uint16_t* __restrict__ Aw,
    const float* __restrict__ lgt, const float* __restrict__ red,
    const float4* __restrict__ vstat,
    const float* __restrict__ gscal, const float* __restrict__ ws_fg,
    const float* __restrict__ featc,
    float* __restrict__ part, float* __restrict__ pscal,
    float* __restrict__ partc, float* __restrict__ out_attn){
  __shared__ float ps[CS_];
  __shared__ float psp[CS_];
  __shared__ float pw[4][64];
  __shared__ float pcz[4][16];
  __shared__ float rsc[4][4];
  int chunk=blockIdx.x, bk=blockIdx.y, b=bk/K_, k=bk-b*K_;
  int tid=threadIdx.x, wid=tid>>6, lane=tid&63, sub=lane>>4, c4=lane&15;
  float mwgx=gscal[0], mwgy=gscal[1], mbg=gscal[2];
  float g1=gscal[3], g2=gscal[4], g3=gscal[5], g4=gscal[6], g5=gscal[7], g6=gscal[8];
  float fgx=ws_fg[k*2+0], fgy=ws_fg[k*2+1];
  const float* rp = red + (size_t)bk*NC_*4;
  float M=-1e30f;
  #pragma unroll
  for(int i=0;i<NC_;i++) M = fmaxf(M, rp[i*4]);
  float S=0.f;
  #pragma unroll
  for(int i=0;i<NC_;i++) S += rp[i*4+1]*__expf(rp[i*4]-M);
  float invS = 1.f/S;
  float amin=0.f, dinv=0.f;
  if(FINAL){
    float LMIN=1e30f;
    #pragma unroll
    for(int i=0;i<NC_;i++) LMIN=fminf(LMIN, rp[i*4+2]);
    amin = __expf(LMIN-M)*invS;
    dinv = 1.f/(invS - amin + 1e-5f);
  }
  const float* lp = lgt + (size_t)bk*N_ + chunk*CS_;
  const float4* vs = vstat + (size_t)b*N_ + chunk*CS_;
  float As=0.f, Ax=0.f, Ay=0.f, Am=0.f;
  #pragma unroll
  for(int i=0;i<2;i++){
    int nl = tid + i*256;
    int n = chunk*CS_ + nl;
    float p = __expf(lp[nl]-M)*invS;
    float4 st = vs[nl];
    float rx = (-1.f + (2.f/63.f)*(n&63)) - fgx;
    float ry = (-1.f + (2.f/63.f)*(n>>6)) - fgy;
    float muv = st.x + rx*mwgx + ry*mwgy + mbg;
    float var = st.y + rx*st.z + ry*st.w
              + (g1*rx*rx + g2*ry*ry + g3*rx*ry + g4*rx + g5*ry + g6) - muv*muv;
    float rsv = rsqrtf(var + EPS);
    float w = p*rsv;
    ps[nl]=w;
    As+=w; Ax=fmaf(w,rx,Ax); Ay=fmaf(w,ry,Ay); Am=fmaf(w,muv,Am);
    if(FINAL){
      psp[nl]=p;
      out_attn[(size_t)bk*N_ + n] = (p - amin)*dinv;
    }
  }
  As=wsum64(As); Ax=wsum64(Ax); Ay=wsum64(Ay); Am=wsum64(Am);
  if(lane==0){ rsc[wid][0]=As; rsc[wid][1]=Ax; rsc[wid][2]=Ay; rsc[wid][3]=Am; }
  __syncthreads();
  if(tid==0){
    float* pp = pscal + ((size_t)bk*NC_+chunk)*4;
    pp[0]=rsc[0][0]+rsc[1][0]+rsc[2][0]+rsc[3][0];
    pp[1]=rsc[0][1]+rsc[1][1]+rsc[2][1]+rsc[3][1];
    pp[2]=rsc[0][2]+rsc[1][2]+rsc[2][2]+rsc[3][2];
    pp[3]=rsc[0][3]+rsc[1][3]+rsc[2][3]+rsc[3][3];
  }
  const uint2* Ab = (const uint2*)Aw + (size_t)b*N_*16 + (size_t)chunk*CS_*16;
  const float* Fb = featc + ((size_t)b*N_ + chunk*CS_)*16;
  float a0=0.f,a1=0.f,a2=0.f,a3=0.f,ac=0.f;
  for(int t=0;t<32;t++){
    int n = wid*128 + t*4 + sub;
    float w = ps[n];
    uint2 u = Ab[(size_t)n*16 + c4];
    a0 += w*__uint_as_float(u.x<<16);
    a1 += w*__uint_as_float(u.x&0xffff0000u);
    a2 += w*__uint_as_float(u.y<<16);
    a3 += w*__uint_as_float(u.y&0xffff0000u);
    if(FINAL) ac += psp[n]*Fb[(size_t)n*16 + c4];
  }
  a0+=__shfl_xor(a0,16,64); a0+=__shfl_xor(a0,32,64);
  a1+=__shfl_xor(a1,16,64); a1+=__shfl_xor(a1,32,64);
  a2+=__shfl_xor(a2,16,64); a2+=__shfl_xor(a2,32,64);
  a3+=__shfl_xor(a3,16,64); a3+=__shfl_xor(a3,32,64);
  if(FINAL){ ac+=__shfl_xor(ac,16,64); ac+=__shfl_xor(ac,32,64); }
  if(lane<16){
    pw[wid][lane*4+0]=a0; pw[wid][lane*4+1]=a1;
    pw[wid][lane*4+2]=a2; pw[wid][lane*4+3]=a3;
    if(FINAL) pcz[wid][lane]=ac;
  }
  __syncthreads();
  if(tid<64){
    part[((size_t)bk*NC_+chunk)*64 + tid] = pw[0][tid]+pw[1][tid]+pw[2][tid]+pw[3][tid];
  }
  if(FINAL && tid<16){
    partc[((size_t)bk*NC_+chunk)*16 + tid] = pcz[0][tid]+pcz[1][tid]+pcz[2][tid]+pcz[3][tid];
  }
}

// final: out_slot = [slot_3, sum of color partials]
__global__ __launch_bounds__(64) void k_final(const float* __restrict__ slot,
    const float* __restrict__ partc, float* __restrict__ out_slot){
  int bk=blockIdx.x, lane=threadIdx.x;
  out_slot[bk*80+lane]=slot[bk*64+lane];
  if(lane<16){
    float s=0.f;
    #pragma unroll
    for(int cch=0;cch<NC_;cch++) s += partc[((size_t)bk*NC_+cch)*16+lane];
    out_slot[bk*80+64+lane]=s;
  }
}

extern "C" void kernel_launch(void* const* d_in, const int* in_sizes, int n_in,
                              void* d_out, int out_size, void* d_ws, size_t ws_size,
                              hipStream_t stream){
  (void)in_sizes; (void)n_in; (void)out_size; (void)ws_size;
  const float* feat = (const float*)d_in[0];
  const float* featc= (const float*)d_in[1];
  const float* mask = (const float*)d_in[2];
  const float* noise= (const float*)d_in[3];
  const float* mu   = (const float*)d_in[4];
  const float* lsg  = (const float*)d_in[5];
  const float* wg   = (const float*)d_in[6];
  const float* bg   = (const float*)d_in[7];
  const float* wk   = (const float*)d_in[8];
  const float* wv   = (const float*)d_in[9];
  const float* lnkg = (const float*)d_in[10];
  const float* lnkb = (const float*)d_in[11];
  const float* wm   = (const float*)d_in[12];
  const float* bm   = (const float*)d_in[13];
  const float* lnqg = (const float*)d_in[14];
  const float* lnqb = (const float*)d_in[15];
  const float* wq   = (const float*)d_in[16];
  const float* wih  = (const float*)d_in[17];
  const float* whh  = (const float*)d_in[18];
  const float* bih  = (const float*)d_in[19];
  const float* bhh  = (const float*)d_in[20];
  const float* lnfg = (const float*)d_in[21];
  const float* lnfb = (const float*)d_in[22];
  const float* lncg = (const float*)d_in[23];
  const float* lncb = (const float*)d_in[24];
  const float* lnrg = (const float*)d_in[25];
  const float* lnrb = (const float*)d_in[26];
  const float* wres = (const float*)d_in[27];
  const float* bres = (const float*)d_in[28];

  float* out = (float*)d_out;
  float* out_slot = out;          // (B,K,80)
  float* out_fg   = out + 6400;   // (B,K,2)
  float* out_attn = out + 6560;   // (B,K,N)

  float* wsf     = (float*)d_ws;
  float* ws_fg   = wsf;                                // 16
  float* ws_bm2  = wsf + 16;                           // 64
  float* ws_fkb  = ws_bm2 + 64;                        // 64
  float* ws_fvb  = ws_fkb + 64;                        // 64
  float* ws_qb   = ws_fvb + 64;                        // 64
  float* ws_br2  = ws_qb + 64;                         // 64
  float* ws_wgx  = ws_br2 + 64;                        // 64
  float* ws_wgy  = ws_wgx + 64;                        // 64
  float* ws_gs   = ws_wgy + 64;                        // 16
  float* ws_wqpT = ws_gs + 16;                         // 4096
  float* ws_wrpT = ws_wqpT + 4096;                     // 4096
  float* ws_wvT  = ws_wrpT + 4096;                     // 4096
  float* ws_wmT  = ws_wvT + 4096;                      // 4096
  float* ws_gw   = ws_wmT + 4096;                      // 24576
  float* ws_fc   = ws_gw + 24576;                      // B*N*C
  float* ws_sl0  = ws_fc + (size_t)B_*N_*C_;           // 5120
  float* ws_sl1  = ws_sl0 + B_*K_*D_;                  // 5120
  float* ws_lgt  = ws_sl1 + B_*K_*D_;                  // B*K*N
  float* ws_red  = ws_lgt + (size_t)B_*K_*N_;          // 80*NC*4
  float* ws_part = ws_red + B_*K_*NC_*4;               // 80*NC*64
  float* ws_psc  = ws_part + (size_t)B_*K_*NC_*64;     // 80*NC*4
  float* ws_pc   = ws_psc + B_*K_*NC_*4;               // 80*NC*16
  float4* ws_kst = (float4*)(ws_pc + B_*K_*NC_*16);    // B*N float4
  float4* ws_vst = ws_kst + (size_t)B_*N_;             // B*N float4
  uint16_t* ws_A = (uint16_t*)(ws_vst + (size_t)B_*N_);// B*N*64 bf16

  k_pre<<<187,256,0,stream>>>(mask,noise,mu,lsg, wm,bm,lnkb, wk,wv,lnfb,
                              wq,lnqg,lnqb, wres,bres,lnrg,lnrb, wih,whh, wg,bg,
                              ws_fg,out_fg, ws_bm2,ws_fkb,ws_fvb,ws_qb,ws_br2,
                              ws_wgx,ws_wgy,ws_gs,
                              ws_wqpT,ws_wrpT,ws_wvT,ws_wmT, ws_gw, ws_sl0);
  k_featln<<<(B_*N_)/64,256,0,stream>>>(feat,wk,wv,lnfg,ws_fkb,ws_fvb,
                                        ws_wgx,ws_wgy,bg,
                                        featc,lncg,lncb,
                                        ws_A,ws_kst,ws_vst,ws_fc);

  dim3 agrid(NC_,B_*K_);
  #define LOGITS_ARGS(SPREV,SCUR) ws_A,ws_kst,SPREV,SCUR,ws_part,ws_psc,ws_gw, \
      bih,bhh,ws_wrpT,ws_br2,ws_wqpT,ws_qb, wm,wk,lnfg,lnkg, \
      ws_fkb,ws_bm2,ws_fvb, ws_wvT,ws_wmT, ws_wgx,ws_wgy,bg, ws_gs,ws_fg, ws_lgt,ws_red
  #define UPDV_ARGS ws_A,ws_lgt,ws_red,ws_vst,ws_gs,ws_fg,ws_fc,ws_part,ws_psc,ws_pc,out_attn

  k_logits<false,false><<<agrid,256,0,stream>>>(LOGITS_ARGS(ws_sl0,ws_sl0));
  k_updv<false><<<agrid,256,0,stream>>>(UPDV_ARGS);
  k_logits<true,false><<<agrid,256,0,stream>>>(LOGITS_ARGS(ws_sl0,ws_sl1));
  k_updv<false><<<agrid,256,0,stream>>>(UPDV_ARGS);
  k_logits<true,false><<<agrid,256,0,stream>>>(LOGITS_ARGS(ws_sl1,ws_sl0));
  k_updv<false><<<agrid,256,0,stream>>>(UPDV_ARGS);
  k_logits<true,true><<<agrid,256,0,stream>>>(LOGITS_ARGS(ws_sl0,ws_sl1));
  k_updv<true><<<agrid,256,0,stream>>>(UPDV_ARGS);
  k_final<<<B_*K_,64,0,stream>>>(ws_sl1, ws_pc, out_slot);
}

// Round 7
// 242.362 us; speedup vs baseline: 2.1502x; 1.0714x over previous
//
#include <hip/hip_runtime.h>
#include <stdint.h>

#define B_ 16
#define H_ 64
#define W_ 64
#define D_ 64
#define C_ 16
#define K_ 5
#define N_ 4096
#define NC_ 8          // attention n-chunks
#define CS_ 512        // chunk size = N_/NC_
#define EPS 1e-5f

typedef __attribute__((ext_vector_type(8))) short bf16x8;
typedef __attribute__((ext_vector_type(4))) float f32x4;

__device__ __forceinline__ float wsum64(float v){
  #pragma unroll
  for(int o=1;o<64;o<<=1) v += __shfl_xor(v,o,64);
  return v;
}
__device__ __forceinline__ float wmax64(float v){
  #pragma unroll
  for(int o=1;o<64;o<<=1) v = fmaxf(v, __shfl_xor(v,o,64));
  return v;
}
__device__ __forceinline__ float wmin64(float v){
  #pragma unroll
  for(int o=1;o<64;o<<=1) v = fminf(v, __shfl_xor(v,o,64));
  return v;
}
__device__ __forceinline__ uint16_t f2bf(float f){
  uint32_t u = __float_as_uint(f);
  u += 0x7fffu + ((u>>16)&1u);
  return (uint16_t)(u>>16);
}

// k_pre: fgpos (0-4) + folded biases (5) + fvb/wgx/wgy/gscal (6)
// + wqpT/wrpT/wvT/wmT (7-70) + gw (71-166) + slot init (167-186)
__global__ __launch_bounds__(256) void k_pre(
    const float* __restrict__ mask, const float* __restrict__ noise,
    const float* __restrict__ mu, const float* __restrict__ lsg,
    const float* __restrict__ wm, const float* __restrict__ bm, const float* __restrict__ lnkb,
    const float* __restrict__ wk, const float* __restrict__ wv, const float* __restrict__ lnfb,
    const float* __restrict__ wq, const float* __restrict__ lnqg, const float* __restrict__ lnqb,
    const float* __restrict__ wres, const float* __restrict__ bres,
    const float* __restrict__ lnrg, const float* __restrict__ lnrb,
    const float* __restrict__ wih, const float* __restrict__ whh,
    const float* __restrict__ wg, const float* __restrict__ bg,
    float* __restrict__ ws_fg, float* __restrict__ out_fg,
    float* __restrict__ bm2, float* __restrict__ fkb, float* __restrict__ fvb,
    float* __restrict__ qb, float* __restrict__ br2,
    float* __restrict__ wgx, float* __restrict__ wgy, float* __restrict__ gscal,
    float* __restrict__ wqpT, float* __restrict__ wrpT,
    float* __restrict__ wvT, float* __restrict__ wmT,
    float* __restrict__ gw, float* __restrict__ slot){
  int bid=blockIdx.x, tid=threadIdx.x;
  if(bid<5){
    int k=bid;
    float sm=0.f, sx=0.f, sy=0.f;
    for(int p=tid; p<H_*W_; p+=256){
      int i=p>>6, j=p&63;
      float m = mask[k*H_*W_ + p];
      float x = -1.f + (2.f/63.f)*j;
      float y = -1.f + (2.f/63.f)*i;
      sm+=m; sx+=m*x; sy+=m*y;
    }
    __shared__ float r0[4], r1[4], r2[4];
    int wid=tid>>6, lane=tid&63;
    sm=wsum64(sm); sx=wsum64(sx); sy=wsum64(sy);
    if(lane==0){ r0[wid]=sm; r1[wid]=sx; r2[wid]=sy; }
    __syncthreads();
    if(tid==0){
      float tm=r0[0]+r0[1]+r0[2]+r0[3];
      float tx=r1[0]+r1[1]+r1[2]+r1[3];
      float ty=r2[0]+r2[1]+r2[2]+r2[3];
      float px = tx/(tm+1e-5f), py = ty/(tm+1e-5f);
      ws_fg[k*2+0]=px; ws_fg[k*2+1]=py;
      for(int b=0;b<B_;b++){ out_fg[(b*K_+k)*2+0]=px; out_fg[(b*K_+k)*2+1]=py; }
    }
  } else if(bid==5){
    int sel=tid>>6, o=tid&63; float s=0.f;
    if(sel==0){ s=bm[o]; for(int d=0;d<64;d++) s+=lnkb[d]*wm[o*64+d]; bm2[o]=s; }
    else if(sel==1){ for(int d=0;d<64;d++) s+=lnqb[d]*wq[o*64+d]; qb[o]=0.125f*s; }
    else if(sel==2){ for(int d=0;d<64;d++) s+=lnrb[d]*wres[o*64+d]; br2[o]=s+bres[o]; }
    else { for(int d=0;d<64;d++) s+=lnfb[d]*wk[o*64+d]; fkb[o]=s; }
  } else if(bid==6){
    int wv4=tid>>6, l=tid&63;
    if(wv4==0){ float s=0.f; for(int d=0;d<64;d++) s+=lnfb[d]*wv[l*64+d]; fvb[l]=s; }
    else if(wv4==1){
      float4 w4 = *(const float4*)(wg + l*4);
      wgx[l]=w4.x-w4.z; wgy[l]=w4.y-w4.w;
    } else if(wv4==2){
      float4 w4 = *(const float4*)(wg + l*4);
      float wx=w4.x-w4.z, wy=w4.y-w4.w, bl=bg[l];
      float t;
      t=wsum64(wx);    if(l==0) gscal[0]=t*(1.f/64.f);
      t=wsum64(wy);    if(l==0) gscal[1]=t*(1.f/64.f);
      t=wsum64(bl);    if(l==0) gscal[2]=t*(1.f/64.f);
      t=wsum64(wx*wx); if(l==0) gscal[3]=t*(1.f/64.f);
      t=wsum64(wy*wy); if(l==0) gscal[4]=t*(1.f/64.f);
      t=wsum64(wx*wy); if(l==0) gscal[5]=t*(2.f/64.f);
      t=wsum64(wx*bl); if(l==0) gscal[6]=t*(2.f/64.f);
      t=wsum64(wy*bl); if(l==0) gscal[7]=t*(2.f/64.f);
      t=wsum64(bl*bl); if(l==0) gscal[8]=t*(1.f/64.f);
    }
  } else if(bid<71){
    int i=(bid-7)*256+tid;           // < 16384
    int a=i>>12, r=i&4095, d=r>>6, o=r&63;
    if(a==0)      wqpT[r]=0.125f*lnqg[d]*wq[o*64+d];
    else if(a==1) wrpT[r]=lnrg[d]*wres[o*64+d];
    else if(a==2) wvT[r]=wv[o*64+d];
    else          wmT[r]=wm[o*64+d];
  } else if(bid<167){
    int i=(bid-71)*256+tid;          // < 24576
    int g6=i>>12, r=i&4095, d=r>>6, o=r&63;
    float v = (g6<3)? wih[(g6*64+o)*64+d] : whh[((g6-3)*64+o)*64+d];
    gw[g6*4096 + d*64 + o] = v;
  } else {
    int i=(bid-167)*256+tid;
    if(i<B_*K_*D_){ int d=i&63; slot[i]=mu[d]+expf(lsg[d])*noise[i]; }
  }
}

// feat LN -> A (bf16); transient MFMA fk/fv rows -> per-row stat float4s; color LN.
__global__ __launch_bounds__(256) void k_featln(const float* __restrict__ feat,
    const float* __restrict__ wk, const float* __restrict__ wv, const float* __restrict__ gf,
    const float* __restrict__ fkb, const float* __restrict__ fvb,
    const float* __restrict__ wgx, const float* __restrict__ wgy, const float* __restrict__ bg,
    const float* __restrict__ fc, const float* __restrict__ gc, const float* __restrict__ bc,
    uint16_t* __restrict__ Aout, float4* __restrict__ kstat, float4* __restrict__ vstat,
    float* __restrict__ fcn){
  int tid=threadIdx.x, wid=tid>>6, lane=tid&63;
  int q=lane>>4, c=lane&15;
  size_t row = (size_t)blockIdx.x*64 + wid*16 + c;
  const float* xp = feat + row*64;
  float x[16];
  *(float4*)&x[0]  = *(const float4*)(xp + q*8);
  *(float4*)&x[4]  = *(const float4*)(xp + q*8 + 4);
  *(float4*)&x[8]  = *(const float4*)(xp + 32 + q*8);
  *(float4*)&x[12] = *(const float4*)(xp + 36 + q*8);
  float s=0.f;
  #pragma unroll
  for(int i=0;i<16;i++) s+=x[i];
  s += __shfl_xor(s,16,64); s += __shfl_xor(s,32,64);
  float mean = s*(1.f/64.f);
  float v=0.f;
  #pragma unroll
  for(int i=0;i<16;i++){ float d=x[i]-mean; v+=d*d; }
  v += __shfl_xor(v,16,64); v += __shfl_xor(v,32,64);
  float rs = rsqrtf(v*(1.f/64.f)+EPS);
  float gl[16];
  *(float4*)&gl[0]  = *(const float4*)(gf + q*8);
  *(float4*)&gl[4]  = *(const float4*)(gf + q*8 + 4);
  *(float4*)&gl[8]  = *(const float4*)(gf + 32 + q*8);
  *(float4*)&gl[12] = *(const float4*)(gf + 36 + q*8);
  bf16x8 A0, A1;
  #pragma unroll
  for(int j=0;j<8;j++){
    A0[j] = (short)f2bf((x[j]  -mean)*rs);
    A1[j] = (short)f2bf((x[8+j]-mean)*rs);
  }
  *(bf16x8*)(Aout + row*64 + q*8) = A0;
  *(bf16x8*)(Aout + row*64 + 32 + q*8) = A1;
  float wgxl[4][4], wgyl[4][4], bgl[4][4];
  #pragma unroll
  for(int ot=0;ot<4;ot++){
    *(float4*)&wgxl[ot][0] = *(const float4*)(wgx + ot*16 + q*4);
    *(float4*)&wgyl[ot][0] = *(const float4*)(wgy + ot*16 + q*4);
    *(float4*)&bgl[ot][0]  = *(const float4*)(bg + ot*16 + q*4);
  }
  #pragma unroll
  for(int mat=0;mat<2;mat++){
    const float* w = mat? wv : wk;
    const float* fb = mat? fvb : fkb;
    float ss=0.f, s2=0.f, dx=0.f, dy=0.f, db=0.f;
    #pragma unroll
    for(int ot=0; ot<4; ot++){
      const float* wp = w + (size_t)(ot*16+c)*64 + q*8;
      bf16x8 W0, W1;
      #pragma unroll
      for(int j=0;j<8;j++){ W0[j]=(short)f2bf(wp[j]*gl[j]); W1[j]=(short)f2bf(wp[32+j]*gl[8+j]); }
      float4 bq = *(const float4*)(fb + ot*16 + q*4);
      f32x4 acc = {bq.x,bq.y,bq.z,bq.w};
      acc = __builtin_amdgcn_mfma_f32_16x16x32_bf16(W0, A0, acc, 0,0,0);
      acc = __builtin_amdgcn_mfma_f32_16x16x32_bf16(W1, A1, acc, 0,0,0);
      #pragma unroll
      for(int r=0;r<4;r++){
        float a=acc[r];
        ss+=a; s2+=a*a;
        dx = fmaf(a, wgxl[ot][r], dx);
        dy = fmaf(a, wgyl[ot][r], dy);
        db = fmaf(a, bgl[ot][r], db);
      }
    }
    ss += __shfl_xor(ss,16,64); ss += __shfl_xor(ss,32,64);
    s2 += __shfl_xor(s2,16,64); s2 += __shfl_xor(s2,32,64);
    dx += __shfl_xor(dx,16,64); dx += __shfl_xor(dx,32,64);
    dy += __shfl_xor(dy,16,64); dy += __shfl_xor(dy,32,64);
    db += __shfl_xor(db,16,64); db += __shfl_xor(db,32,64);
    if(lane<16){
      size_t row2 = (size_t)blockIdx.x*64 + wid*16 + lane;
      float4 st = { ss*(1.f/64.f), s2*(1.f/64.f)+db*(1.f/32.f), dx*(1.f/32.f), dy*(1.f/32.f) };
      (mat? vstat : kstat)[row2] = st;
    }
  }
  int r16=tid>>4, cc=tid&15;
  #pragma unroll
  for(int i=0;i<4;i++){
    size_t row2 = (size_t)blockIdx.x*64 + i*16 + r16;
    float xv = fc[row2*16+cc];
    float sc=xv;
    #pragma unroll
    for(int o=1;o<16;o<<=1) sc += __shfl_xor(sc,o,16);
    float m2 = sc*(1.f/16.f);
    float df = xv-m2;
    float v2 = df*df;
    #pragma unroll
    for(int o=1;o<16;o<<=1) v2 += __shfl_xor(v2,o,16);
    fcn[row2*16+cc] = df*rsqrtf(v2*(1.f/16.f)+EPS)*gc[cc] + bc[cc];
  }
}

// Fused per-iteration attention: wave0 [GRU merge w/ lambda rescale] + q chain;
// all waves: logits via algebraic K, chunk-local softmax, chunk-local w'=e*rs_v
// weighted A-accumulation (non-final) or lgt store (final).
template<bool GRU, bool FINAL>
__global__ __launch_bounds__(256) void k_attn(const uint16_t* __restrict__ Aw,
    const float4* __restrict__ kstat, const float4* __restrict__ vstat,
    const float* __restrict__ slot_prev, float* __restrict__ slot_cur,
    const float* __restrict__ part, const float* __restrict__ pscal,
    const float* __restrict__ gw,
    const float* __restrict__ bih, const float* __restrict__ bhh,
    const float* __restrict__ wrpT, const float* __restrict__ br2,
    const float* __restrict__ wqpT, const float* __restrict__ qb,
    const float* __restrict__ wm, const float* __restrict__ wk,
    const float* __restrict__ lnfg, const float* __restrict__ lnkg,
    const float* __restrict__ fkb, const float* __restrict__ bm2, const float* __restrict__ fvb,
    const float* __restrict__ wvT, const float* __restrict__ wmT,
    const float* __restrict__ wgx, const float* __restrict__ wgy, const float* __restrict__ bg,
    const float* __restrict__ gscal, const float* __restrict__ ws_fg,
    float* __restrict__ lgt, float* __restrict__ red,
    float* __restrict__ part_o, float* __restrict__ pscal_o){
  __shared__ float qs[64];
  __shared__ float cst[5];
  __shared__ float rm[4], rn[4];
  __shared__ float rsc[4][5];
  __shared__ float ps[CS_];
  __shared__ float pw[4][64];
  int chunk=blockIdx.x, bk=blockIdx.y, b=bk/K_, k=bk-b*K_;
  int tid=threadIdx.x, wid=tid>>6, lane=tid&63, sub=lane>>4, c4=lane&15;
  float mwgx=gscal[0], mwgy=gscal[1], mbg=gscal[2];
  float g1=gscal[3], g2=gscal[4], g3=gscal[5], g4=gscal[6], g5=gscal[7], g6=gscal[8];
  float fgx=ws_fg[k*2+0], fgy=ws_fg[k*2+1];
  if(wid==0){
    float cur;
    if(GRU){
      // merge previous iteration's chunk-local partials with exact rescale
      float mred[NC_], sred[NC_];
      #pragma unroll
      for(int cc=0;cc<NC_;cc++){
        const float* rp = red + ((size_t)bk*NC_+cc)*4;
        mred[cc]=rp[0]; sred[cc]=rp[1];
      }
      float M=-1e30f;
      #pragma unroll
      for(int cc=0;cc<NC_;cc++) M=fmaxf(M,mred[cc]);
      float S=0.f;
      #pragma unroll
      for(int cc=0;cc<NC_;cc++){ mred[cc]=__expf(mred[cc]-M); S=fmaf(sred[cc],mred[cc],S); }
      float invS=1.f/S;
      float sA=0.f, As=0.f, Ax=0.f, Ay=0.f, Am=0.f;
      #pragma unroll
      for(int cc=0;cc<NC_;cc++){
        float lam = mred[cc]*invS;
        sA = fmaf(lam, part[((size_t)bk*NC_+cc)*64+lane], sA);
        const float* pp = pscal + ((size_t)bk*NC_+cc)*4;
        As=fmaf(lam,pp[0],As); Ax=fmaf(lam,pp[1],Ax);
        Ay=fmaf(lam,pp[2],Ay); Am=fmaf(lam,pp[3],Am);
      }
      float sAp = lnfg[lane]*sA;
      float fvs = fvb[lane]*As;
      #pragma unroll 8
      for(int d=0;d<64;d++) fvs = fmaf(__shfl(sAp,d,64), wvT[d*64+lane], fvs);
      float zs = fvs + Ax*wgx[lane] + Ay*wgy[lane] + As*bg[lane] - Am;
      float zsp = lnkg[lane]*zs;
      float x = bm2[lane];
      #pragma unroll 8
      for(int d=0;d<64;d++) x = fmaf(__shfl(zsp,d,64), wmT[d*64+lane], x);
      float hp = slot_prev[bk*64+lane];
      float gir=bih[lane], giz=bih[64+lane], gin=bih[128+lane];
      float ghr=bhh[lane], ghz=bhh[64+lane], ghn=bhh[128+lane];
      #pragma unroll 8
      for(int d=0;d<64;d++){
        float xd=__shfl(x,d,64), hd=__shfl(hp,d,64);
        gir = fmaf(xd, gw[d*64+lane], gir);
        giz = fmaf(xd, gw[4096+d*64+lane], giz);
        gin = fmaf(xd, gw[8192+d*64+lane], gin);
        ghr = fmaf(hd, gw[12288+d*64+lane], ghr);
        ghz = fmaf(hd, gw[16384+d*64+lane], ghz);
        ghn = fmaf(hd, gw[20480+d*64+lane], ghn);
      }
      float r=1.f/(1.f+__expf(-(gir+ghr)));
      float z=1.f/(1.f+__expf(-(giz+ghz)));
      float nn=tanhf(gin+r*ghn);
      float sp=(1.f-z)*nn+z*hp;
      float m=wsum64(sp)*(1.f/64.f); float df=sp-m;
      float var=wsum64(df*df)*(1.f/64.f);
      float dr=df*rsqrtf(var+EPS);
      float a=br2[lane]+hp;
      #pragma unroll 8
      for(int d=0;d<64;d++) a = fmaf(__shfl(dr,d,64), wrpT[d*64+lane], a);
      cur = a;
      if(chunk==0) slot_cur[bk*64+lane]=a;
    } else {
      cur = slot_prev[bk*64+lane];
    }
    float m=wsum64(cur)*(1.f/64.f); float df=cur-m;
    float var=wsum64(df*df)*(1.f/64.f);
    float dr=df*rsqrtf(var+EPS);
    float qv=qb[lane];
    #pragma unroll 8
    for(int d=0;d<64;d++) qv = fmaf(__shfl(dr,d,64), wqpT[d*64+lane], qv);
    float qp=0.f;
    #pragma unroll 8
    for(int o=0;o<64;o++) qp = fmaf(__shfl(qv,o,64), wm[o*64+lane], qp);
    qp *= lnkg[lane];
    float qpp=0.f;
    #pragma unroll 8
    for(int o=0;o<64;o++) qpp = fmaf(__shfl(qp,o,64), wk[o*64+lane], qpp);
    qpp *= lnfg[lane];
    qs[lane]=qpp;
    float s1 = wsum64(qp);
    float c1 = wsum64(qp*wgx[lane]);
    float c2 = wsum64(qp*wgy[lane]);
    float c3 = wsum64(qp*(bg[lane]+fkb[lane]));
    float c4 = wsum64(qv*bm2[lane]);
    if(lane==0){
      cst[0]=c1-s1*mwgx; cst[1]=c2-s1*mwgy; cst[2]=c3-s1*mbg; cst[3]=s1; cst[4]=c4;
    }
  }
  __syncthreads();
  float CX=cst[0], CY=cst[1], C0=cst[2], S1=cst[3], C4=cst[4];
  const uint4* Ab = (const uint4*)Aw + (size_t)b*N_*8 + (size_t)chunk*CS_*8;
  const float4* ks = kstat + (size_t)b*N_ + chunk*CS_;
  const float4* vs = vstat + (size_t)b*N_ + chunk*CS_;
  float l[2], rsv[2], rxv[2], ryv[2], muv[2];
  #pragma unroll
  for(int i=0;i<2;i++){
    int nl = tid + i*256;
    int n = chunk*CS_ + nl;
    float dot=0.f;
    #pragma unroll
    for(int j=0;j<8;j++){
      uint4 u = Ab[(size_t)nl*8+j];
      dot += __uint_as_float(u.x<<16)          * qs[j*8+0]
           + __uint_as_float(u.x&0xffff0000u)  * qs[j*8+1]
           + __uint_as_float(u.y<<16)          * qs[j*8+2]
           + __uint_as_float(u.y&0xffff0000u)  * qs[j*8+3]
           + __uint_as_float(u.z<<16)          * qs[j*8+4]
           + __uint_as_float(u.z&0xffff0000u)  * qs[j*8+5]
           + __uint_as_float(u.w<<16)          * qs[j*8+6]
           + __uint_as_float(u.w&0xffff0000u)  * qs[j*8+7];
    }
    float rx = (-1.f + (2.f/63.f)*(n&63)) - fgx;
    float ry = (-1.f + (2.f/63.f)*(n>>6)) - fgy;
    float4 st = ks[nl];
    float mu = st.x + rx*mwgx + ry*mwgy + mbg;
    float var = st.y + rx*st.z + ry*st.w
              + (g1*rx*rx + g2*ry*ry + g3*rx*ry + g4*rx + g5*ry + g6) - mu*mu;
    float rsn = rsqrtf(var + EPS);
    float a = rsn*(dot + rx*CX + ry*CY + C0 - S1*st.x) + C4;
    l[i]=a;
    if(FINAL) lgt[(size_t)bk*N_ + n] = a;
    if(!FINAL){
      float4 sv = vs[nl];
      float muV = sv.x + rx*mwgx + ry*mwgy + mbg;
      float varV = sv.y + rx*sv.z + ry*sv.w
                 + (g1*rx*rx + g2*ry*ry + g3*rx*ry + g4*rx + g5*ry + g6) - muV*muV;
      rsv[i] = rsqrtf(varV + EPS);
      rxv[i]=rx; ryv[i]=ry; muv[i]=muV;
    }
  }
  float wm_ = wmax64(fmaxf(l[0],l[1]));
  if(lane==0) rm[wid]=wm_;
  if(FINAL){ float mn=wmin64(fminf(l[0],l[1])); if(lane==0) rn[wid]=mn; }
  __syncthreads();
  float m_c = fmaxf(fmaxf(rm[0],rm[1]),fmaxf(rm[2],rm[3]));
  float e0=__expf(l[0]-m_c), e1=__expf(l[1]-m_c);
  float sc=e0+e1;
  float As=0.f, Ax=0.f, Ay=0.f, Am=0.f;
  if(!FINAL){
    float w0=e0*rsv[0], w1=e1*rsv[1];
    ps[tid]=w0; ps[tid+256]=w1;
    As=w0+w1;
    Ax=fmaf(w0,rxv[0],w1*rxv[1]);
    Ay=fmaf(w0,ryv[0],w1*ryv[1]);
    Am=fmaf(w0,muv[0],w1*muv[1]);
  }
  sc=wsum64(sc);
  if(!FINAL){ As=wsum64(As); Ax=wsum64(Ax); Ay=wsum64(Ay); Am=wsum64(Am); }
  if(lane==0){ rsc[wid][0]=sc; rsc[wid][1]=As; rsc[wid][2]=Ax; rsc[wid][3]=Ay; rsc[wid][4]=Am; }
  __syncthreads();
  if(tid==0){
    float* rp = red + ((size_t)bk*NC_+chunk)*4;
    rp[0]=m_c;
    rp[1]=rsc[0][0]+rsc[1][0]+rsc[2][0]+rsc[3][0];
    if(FINAL) rp[2]=fminf(fminf(rn[0],rn[1]),fminf(rn[2],rn[3]));
    if(!FINAL){
      float* pp = pscal_o + ((size_t)bk*NC_+chunk)*4;
      pp[0]=rsc[0][1]+rsc[1][1]+rsc[2][1]+rsc[3][1];
      pp[1]=rsc[0][2]+rsc[1][2]+rsc[2][2]+rsc[3][2];
      pp[2]=rsc[0][3]+rsc[1][3]+rsc[2][3]+rsc[3][3];
      pp[3]=rsc[0][4]+rsc[1][4]+rsc[2][4]+rsc[3][4];
    }
  }
  if(!FINAL){
    const uint2* Ab2 = (const uint2*)Aw + (size_t)b*N_*16 + (size_t)chunk*CS_*16;
    float a0=0.f,a1=0.f,a2=0.f,a3=0.f;
    for(int t=0;t<32;t++){
      int n = wid*128 + t*4 + sub;
      float w = ps[n];
      uint2 u = Ab2[(size_t)n*16 + c4];
      a0 += w*__uint_as_float(u.x<<16);
      a1 += w*__uint_as_float(u.x&0xffff0000u);
      a2 += w*__uint_as_float(u.y<<16);
      a3 += w*__uint_as_float(u.y&0xffff0000u);
    }
    a0+=__shfl_xor(a0,16,64); a0+=__shfl_xor(a0,32,64);
    a1+=__shfl_xor(a1,16,64); a1+=__shfl_xor(a1,32,64);
    a2+=__shfl_xor(a2,16,64); a2+=__shfl_xor(a2,32,64);
    a3+=__shfl_xor(a3,16,64); a3+=__shfl_xor(a3,32,64);
    if(lane<16){
      pw[wid][lane*4+0]=a0; pw[wid][lane*4+1]=a1;
      pw[wid][lane*4+2]=a2; pw[wid][lane*4+3]=a3;
    }
    __syncthreads();
    if(tid<64){
      part_o[((size_t)bk*NC_+chunk)*64 + tid] = pw[0][tid]+pw[1][tid]+pw[2][tid]+pw[3][tid];
    }
  }
}

// final pass 2: p from global stats; out_attn; color partials
__global__ __launch_bounds__(256) void k_fin(const float* __restrict__ lgt,
    const float* __restrict__ red, const float* __restrict__ featc,
    float* __restrict__ partc, float* __restrict__ out_attn){
  __shared__ float psp[CS_];
  __shared__ float pcz[4][16];
  int chunk=blockIdx.x, bk=blockIdx.y, b=bk/K_;
  int tid=threadIdx.x, wid=tid>>6, lane=tid&63, sub=lane>>4, c4=lane&15;
  const float* rp = red + (size_t)bk*NC_*4;
  float M=-1e30f;
  #pragma unroll
  for(int i=0;i<NC_;i++) M = fmaxf(M, rp[i*4]);
  float S=0.f;
  #pragma unroll
  for(int i=0;i<NC_;i++) S += rp[i*4+1]*__expf(rp[i*4]-M);
  float invS = 1.f/S;
  float LMIN=1e30f;
  #pragma unroll
  for(int i=0;i<NC_;i++) LMIN=fminf(LMIN, rp[i*4+2]);
  float amin = __expf(LMIN-M)*invS;
  float dinv = 1.f/(invS - amin + 1e-5f);
  const float* lp = lgt + (size_t)bk*N_ + chunk*CS_;
  #pragma unroll
  for(int i=0;i<2;i++){
    int nl = tid + i*256;
    float p = __expf(lp[nl]-M)*invS;
    psp[nl]=p;
    out_attn[(size_t)bk*N_ + chunk*CS_ + nl] = (p - amin)*dinv;
  }
  __syncthreads();
  const float* Fb = featc + ((size_t)b*N_ + chunk*CS_)*16;
  float ac=0.f;
  for(int t=0;t<32;t++){
    int n = wid*128 + t*4 + sub;
    ac += psp[n]*Fb[(size_t)n*16 + c4];
  }
  ac+=__shfl_xor(ac,16,64); ac+=__shfl_xor(ac,32,64);
  if(lane<16) pcz[wid][lane]=ac;
  __syncthreads();
  if(tid<16){
    partc[((size_t)bk*NC_+chunk)*16 + tid] = pcz[0][tid]+pcz[1][tid]+pcz[2][tid]+pcz[3][tid];
  }
}

// final: out_slot = [slot_3, sum of color partials]
__global__ __launch_bounds__(64) void k_final(const float* __restrict__ slot,
    const float* __restrict__ partc, float* __restrict__ out_slot){
  int bk=blockIdx.x, lane=threadIdx.x;
  out_slot[bk*80+lane]=slot[bk*64+lane];
  if(lane<16){
    float s=0.f;
    #pragma unroll
    for(int cch=0;cch<NC_;cch++) s += partc[((size_t)bk*NC_+cch)*16+lane];
    out_slot[bk*80+64+lane]=s;
  }
}

extern "C" void kernel_launch(void* const* d_in, const int* in_sizes, int n_in,
                              void* d_out, int out_size, void* d_ws, size_t ws_size,
                              hipStream_t stream){
  (void)in_sizes; (void)n_in; (void)out_size; (void)ws_size;
  const float* feat = (const float*)d_in[0];
  const float* featc= (const float*)d_in[1];
  const float* mask = (const float*)d_in[2];
  const float* noise= (const float*)d_in[3];
  const float* mu   = (const float*)d_in[4];
  const float* lsg  = (const float*)d_in[5];
  const float* wg   = (const float*)d_in[6];
  const float* bg   = (const float*)d_in[7];
  const float* wk   = (const float*)d_in[8];
  const float* wv   = (const float*)d_in[9];
  const float* lnkg = (const float*)d_in[10];
  const float* lnkb = (const float*)d_in[11];
  const float* wm   = (const float*)d_in[12];
  const float* bm   = (const float*)d_in[13];
  const float* lnqg = (const float*)d_in[14];
  const float* lnqb = (const float*)d_in[15];
  const float* wq   = (const float*)d_in[16];
  const float* wih  = (const float*)d_in[17];
  const float* whh  = (const float*)d_in[18];
  const float* bih  = (const float*)d_in[19];
  const float* bhh  = (const float*)d_in[20];
  const float* lnfg = (const float*)d_in[21];
  const float* lnfb = (const float*)d_in[22];
  const float* lncg = (const float*)d_in[23];
  const float* lncb = (const float*)d_in[24];
  const float* lnrg = (const float*)d_in[25];
  const float* lnrb = (const float*)d_in[26];
  const float* wres = (const float*)d_in[27];
  const float* bres = (const float*)d_in[28];

  float* out = (float*)d_out;
  float* out_slot = out;          // (B,K,80)
  float* out_fg   = out + 6400;   // (B,K,2)
  float* out_attn = out + 6560;   // (B,K,N)

  float* wsf     = (float*)d_ws;
  float* ws_fg   = wsf;                                // 16
  float* ws_bm2  = wsf + 16;                           // 64
  float* ws_fkb  = ws_bm2 + 64;                        // 64
  float* ws_fvb  = ws_fkb + 64;                        // 64
  float* ws_qb   = ws_fvb + 64;                        // 64
  float* ws_br2  = ws_qb + 64;                         // 64
  float* ws_wgx  = ws_br2 + 64;                        // 64
  float* ws_wgy  = ws_wgx + 64;                        // 64
  float* ws_gs   = ws_wgy + 64;                        // 16
  float* ws_wqpT = ws_gs + 16;                         // 4096
  float* ws_wrpT = ws_wqpT + 4096;                     // 4096
  float* ws_wvT  = ws_wrpT + 4096;                     // 4096
  float* ws_wmT  = ws_wvT + 4096;                      // 4096
  float* ws_gw   = ws_wmT + 4096;                      // 24576
  float* ws_fc   = ws_gw + 24576;                      // B*N*C
  float* ws_sl0  = ws_fc + (size_t)B_*N_*C_;           // 5120
  float* ws_sl1  = ws_sl0 + B_*K_*D_;                  // 5120
  float* ws_lgt  = ws_sl1 + B_*K_*D_;                  // B*K*N
  float* ws_red  = ws_lgt + (size_t)B_*K_*N_;          // 80*NC*4
  float* ws_part = ws_red + B_*K_*NC_*4;               // 80*NC*64
  float* ws_psc  = ws_part + (size_t)B_*K_*NC_*64;     // 80*NC*4
  float* ws_pc   = ws_psc + B_*K_*NC_*4;               // 80*NC*16
  float4* ws_kst = (float4*)(ws_pc + B_*K_*NC_*16);    // B*N float4
  float4* ws_vst = ws_kst + (size_t)B_*N_;             // B*N float4
  uint16_t* ws_A = (uint16_t*)(ws_vst + (size_t)B_*N_);// B*N*64 bf16

  k_pre<<<187,256,0,stream>>>(mask,noise,mu,lsg, wm,bm,lnkb, wk,wv,lnfb,
                              wq,lnqg,lnqb, wres,bres,lnrg,lnrb, wih,whh, wg,bg,
                              ws_fg,out_fg, ws_bm2,ws_fkb,ws_fvb,ws_qb,ws_br2,
                              ws_wgx,ws_wgy,ws_gs,
                              ws_wqpT,ws_wrpT,ws_wvT,ws_wmT, ws_gw, ws_sl0);
  k_featln<<<(B_*N_)/64,256,0,stream>>>(feat,wk,wv,lnfg,ws_fkb,ws_fvb,
                                        ws_wgx,ws_wgy,bg,
                                        featc,lncg,lncb,
                                        ws_A,ws_kst,ws_vst,ws_fc);

  dim3 agrid(NC_,B_*K_);
  #define ATTN_ARGS(SPREV,SCUR) ws_A,ws_kst,ws_vst,SPREV,SCUR,ws_part,ws_psc,ws_gw, \
      bih,bhh,ws_wrpT,ws_br2,ws_wqpT,ws_qb, wm,wk,lnfg,lnkg, \
      ws_fkb,ws_bm2,ws_fvb, ws_wvT,ws_wmT, ws_wgx,ws_wgy,bg, ws_gs,ws_fg, \
      ws_lgt,ws_red,ws_part,ws_psc

  k_attn<false,false><<<agrid,256,0,stream>>>(ATTN_ARGS(ws_sl0,ws_sl0));
  k_attn<true,false><<<agrid,256,0,stream>>>(ATTN_ARGS(ws_sl0,ws_sl1));
  k_attn<true,false><<<agrid,256,0,stream>>>(ATTN_ARGS(ws_sl1,ws_sl0));
  k_attn<true,true><<<agrid,256,0,stream>>>(ATTN_ARGS(ws_sl0,ws_sl1));
  k_fin<<<agrid,256,0,stream>>>(ws_lgt,ws_red,ws_fc,ws_pc,out_attn);
  k_final<<<B_*K_,64,0,stream>>>(ws_sl1, ws_pc, out_slot);
}